// Round 5
// baseline (397.678 us; speedup 1.0000x reference)
//
#include <hip/hip_runtime.h>
#include <hip/hip_bf16.h>
#include <math.h>

#define B_   2
#define S_   2048
#define D_   1024
#define H_   16
#define DK_  64
#define F_   4096
#define NTOK (B_ * S_)

typedef __bf16 bf16x8 __attribute__((ext_vector_type(8)));
typedef float  f32x4  __attribute__((ext_vector_type(4)));

__device__ __forceinline__ unsigned short bf16r(float f) {
  unsigned u = __builtin_bit_cast(unsigned, f);
  u += 0x7fffu + ((u >> 16) & 1u);
  return (unsigned short)(u >> 16);
}

__device__ __forceinline__ void gload_lds16(const void* g, void* l) {
  __builtin_amdgcn_global_load_lds(
      (__attribute__((address_space(1))) void*)g,
      (__attribute__((address_space(3))) void*)l, 16, 0, 0);
}

// tanh-form GELU via exp2 (max abs err ~3e-3 vs exact erf form)
__device__ __forceinline__ float gelu_fast(float x) {
  float y = 0.7978845608f * x * (1.0f + 0.044715f * x * x);
  float e = exp2f(2.885390082f * y);  // e^(2y)
  float t = 1.0f - 2.0f / (e + 1.0f);
  return 0.5f * x * (1.0f + t);
}

// ---------------- all weights fp32 -> bf16, one launch ----------------
struct CvtArgs {
  const float* src[6];
  unsigned short* dst[6];
  int start[7];
};
__global__ __launch_bounds__(256) void cvt_all_kernel(CvtArgs a) {
  int i = blockIdx.x * blockDim.x + threadIdx.x;  // float4 chunk index
  if (i >= a.start[6]) return;
  int k = 0;
#pragma unroll
  for (int j = 1; j < 6; ++j)
    if (i >= a.start[j]) k = j;
  int off = i - a.start[k];
  float4 v = reinterpret_cast<const float4*>(a.src[k])[off];
  ushort4 o;
  o.x = bf16r(v.x); o.y = bf16r(v.y); o.z = bf16r(v.z); o.w = bf16r(v.w);
  reinterpret_cast<ushort4*>(a.dst[k])[off] = o;
}

// ---------------- RMSNorm (fp32 in, bf16 out) ----------------
__global__ __launch_bounds__(256) void rmsnorm_kernel(
    const float* __restrict__ x, const float* __restrict__ g,
    unsigned short* __restrict__ out) {
  int row = blockIdx.x;
  int t = threadIdx.x, lane = t & 63, w = t >> 6;
  float4 v = reinterpret_cast<const float4*>(x + (size_t)row * D_)[t];
  float ss = v.x * v.x + v.y * v.y + v.z * v.z + v.w * v.w;
#pragma unroll
  for (int d = 1; d < 64; d <<= 1) ss += __shfl_xor(ss, d);
  __shared__ float red[4];
  if (lane == 0) red[w] = ss;
  __syncthreads();
  float tot = red[0] + red[1] + red[2] + red[3];
  float rstd = rsqrtf(tot * (1.0f / D_) + 1e-5f);
  float4 gv = reinterpret_cast<const float4*>(g)[t];
  ushort4 o;
  o.x = bf16r(v.x * rstd * gv.x);
  o.y = bf16r(v.y * rstd * gv.y);
  o.z = bf16r(v.z * rstd * gv.z);
  o.w = bf16r(v.w * rstd * gv.w);
  reinterpret_cast<ushort4*>(out + (size_t)row * D_)[t] = o;
}

// ======== direct-register GEMM (no LDS, no barriers): C = A * Bw^T ==========
// 128x128 tile, 256 thr / 4 waves (2x2), per-wave 64x64 = 4x4 frags.
// Fragments loaded straight from global (L1 absorbs intra-block re-touch),
// software-pipelined one K32-tile ahead with static ping-pong registers.
// EPI 1: fast-GELU->bf16 | 5: QKV row-major 3-way split
template <int TAG, int EPI>
__global__ __launch_bounds__(256, 3) void gemm_reg(
    const unsigned short* __restrict__ A, const unsigned short* __restrict__ Bw,
    int M, int N, int K,
    unsigned short* __restrict__ o1, unsigned short* __restrict__ o2,
    unsigned short* __restrict__ o3) {
  const int t = threadIdx.x, lane = t & 63, w = t >> 6;
  const int wm = w >> 1, wn = w & 1;
  const int lg = lane >> 4, ln = lane & 15;

  // bijective XCD-aware remap (gridDim.x%4==0, gridDim.y%2==0)
  const int gx = gridDim.x;
  int bid = blockIdx.y * gx + blockIdx.x;
  int xcd = bid & 7, c = bid >> 3;
  int RX = gx >> 2, RY = gridDim.y >> 1;
  int bx = (xcd & 3) * RX + (c % RX);
  int by = (xcd >> 2) * RY + (c / RX);
  const int m0 = by * 128, n0 = bx * 128;

  const unsigned short* pa[4];
  const unsigned short* pb[4];
#pragma unroll
  for (int m = 0; m < 4; ++m)
    pa[m] = A + (size_t)(m0 + wm * 64 + m * 16 + ln) * K + lg * 8;
#pragma unroll
  for (int n = 0; n < 4; ++n)
    pb[n] = Bw + (size_t)(n0 + wn * 64 + n * 16 + ln) * K + lg * 8;

  f32x4 acc[4][4] = {};
  bf16x8 a0[4], b0[4], a1[4], b1[4];
#pragma unroll
  for (int m = 0; m < 4; ++m) a0[m] = *reinterpret_cast<const bf16x8*>(pa[m]);
#pragma unroll
  for (int n = 0; n < 4; ++n) b0[n] = *reinterpret_cast<const bf16x8*>(pb[n]);

  const int nt = K >> 5;  // 32 or 128, even
  for (int kt = 0; kt < nt; kt += 2) {
    // prefetch tile kt+1 (always exists: nt even)
#pragma unroll
    for (int m = 0; m < 4; ++m)
      a1[m] = *reinterpret_cast<const bf16x8*>(pa[m] + (kt + 1) * 32);
#pragma unroll
    for (int n = 0; n < 4; ++n)
      b1[n] = *reinterpret_cast<const bf16x8*>(pb[n] + (kt + 1) * 32);
    // compute tile kt
#pragma unroll
    for (int m = 0; m < 4; ++m)
#pragma unroll
      for (int n = 0; n < 4; ++n)
        acc[m][n] = __builtin_amdgcn_mfma_f32_16x16x32_bf16(a0[m], b0[n], acc[m][n], 0, 0, 0);
    // prefetch tile kt+2
    if (kt + 2 < nt) {
#pragma unroll
      for (int m = 0; m < 4; ++m)
        a0[m] = *reinterpret_cast<const bf16x8*>(pa[m] + (kt + 2) * 32);
#pragma unroll
      for (int n = 0; n < 4; ++n)
        b0[n] = *reinterpret_cast<const bf16x8*>(pb[n] + (kt + 2) * 32);
    }
    // compute tile kt+1
#pragma unroll
    for (int m = 0; m < 4; ++m)
#pragma unroll
      for (int n = 0; n < 4; ++n)
        acc[m][n] = __builtin_amdgcn_mfma_f32_16x16x32_bf16(a1[m], b1[n], acc[m][n], 0, 0, 0);
  }

  const int rbase = m0 + wm * 64 + lg * 4;
  const int cbase = n0 + wn * 64 + ln;
#pragma unroll
  for (int m = 0; m < 4; ++m) {
#pragma unroll
    for (int n = 0; n < 4; ++n) {
      int col = cbase + n * 16;
#pragma unroll
      for (int j = 0; j < 4; ++j) {
        int row = rbase + m * 16 + j;
        float v = acc[m][n][j];
        if (EPI == 1) {
          o1[(size_t)row * N + col] = bf16r(gelu_fast(v));
        } else {  // EPI 5: QKV row-major split
          if (col < D_)           o1[(size_t)row * D_ + col] = bf16r(v);
          else if (col < 2 * D_)  o2[(size_t)row * D_ + (col - D_)] = bf16r(v);
          else                    o3[(size_t)row * D_ + (col - 2 * D_)] = bf16r(v);
        }
      }
    }
  }
}

// ---------------- V transpose: [b,s,d] -> [b,d,s] (64x64 LDS tiles) ---------
__global__ __launch_bounds__(256) void vtrans_kernel(
    const unsigned short* __restrict__ v, unsigned short* __restrict__ vt) {
  __shared__ unsigned short tile[64][68];
  const int t = threadIdx.x;
  const int row0 = blockIdx.x * 64;  // global token-row base (b*2048 + s)
  const int d0 = blockIdx.y * 64;
  const int b = row0 >> 11, s0 = row0 & (S_ - 1);
  const int r = t >> 4, c4 = (t & 15) * 4;
#pragma unroll
  for (int i = 0; i < 4; ++i) {
    ushort4 vv = *reinterpret_cast<const ushort4*>(
        &v[(size_t)(row0 + r + i * 16) * D_ + d0 + c4]);
    tile[r + i * 16][c4 + 0] = vv.x;
    tile[r + i * 16][c4 + 1] = vv.y;
    tile[r + i * 16][c4 + 2] = vv.z;
    tile[r + i * 16][c4 + 3] = vv.w;
  }
  __syncthreads();
#pragma unroll
  for (int i = 0; i < 4; ++i) {
    int d = r + i * 16;
    ushort4 o;
    o.x = tile[c4 + 0][d];
    o.y = tile[c4 + 1][d];
    o.z = tile[c4 + 2][d];
    o.w = tile[c4 + 3][d];
    *reinterpret_cast<ushort4*>(
        &vt[(size_t)(b * D_ + d0 + d) * S_ + s0 + c4]) = o;
  }
}

// ---------------- 128x128 pipelined LDS GEMM (4-deep) for N=1024 outputs ----
// EPI 2: +resid -> fp32. TAG only disambiguates profile names.
template <int TAG>
__global__ __launch_bounds__(512, 4) void gemm_pipe(
    const unsigned short* __restrict__ A, const unsigned short* __restrict__ Bw,
    int M, int N, int K,
    const float* __restrict__ resid, float* __restrict__ outF) {
  constexpr int TM = 128, TN = 128;
  constexpr int NBUF = 4;
  constexpr int MR = TM / 32;
  constexpr int NR = TN / 64;
  constexpr int LA = TM * 4 / 512;
  constexpr int LB = TN * 4 / 512;
  constexpr int BUFU = (TM + TN) * 32;
  __shared__ __attribute__((aligned(16))) unsigned short lds[NBUF * BUFU];

  const int t = threadIdx.x, lane = t & 63, w = t >> 6;
  const int wm = w >> 2, wn = w & 3;
  const int lg = lane >> 4, ln = lane & 15;

  const int gx = gridDim.x;
  int bid = blockIdx.y * gx + blockIdx.x;
  int RX = gx >> 2, RY = gridDim.y >> 1;
  int xcd = bid & 7, c = bid >> 3;
  int bx = (xcd & 3) * RX + (c % RX);
  int by = (xcd >> 2) * RY + (c / RX);
  const int m0 = by * TM, n0 = bx * TN;

  const int nt = K >> 5;

  auto stage = [&](int tile) {
    const int buf = tile & (NBUF - 1);
    const int k0 = tile << 5;
    unsigned short* la = &lds[buf * BUFU];
    unsigned short* lb = la + TM * 32;
#pragma unroll
    for (int i = 0; i < LA; ++i) {
      int g = i * 512 + t;
      int Ln = g >> 3, p = g & 7, u = p ^ (Ln & 7);
      int row = 2 * Ln + (u >> 2), cg = u & 3;
      gload_lds16(A + (size_t)(m0 + row) * K + k0 + cg * 8, &la[g * 8]);
    }
#pragma unroll
    for (int i = 0; i < LB; ++i) {
      int g = i * 512 + t;
      int Ln = g >> 3, p = g & 7, u = p ^ (Ln & 7);
      int row = 2 * Ln + (u >> 2), cg = u & 3;
      gload_lds16(Bw + (size_t)(n0 + row) * K + k0 + cg * 8, &lb[g * 8]);
    }
  };

  stage(0);
  if (nt > 1) stage(1);
  if (nt > 2) stage(2);

  int offA[MR], offB[NR];
#pragma unroll
  for (int m = 0; m < MR; ++m) {
    int r = wm * (TM / 2) + m * 16 + ln;
    int Ln = r >> 1, p = ((r & 1) * 4 + lg) ^ (Ln & 7);
    offA[m] = Ln * 64 + p * 8;
  }
#pragma unroll
  for (int n = 0; n < NR; ++n) {
    int r = wn * (TN / 4) + n * 16 + ln;
    int Ln = r >> 1, p = ((r & 1) * 4 + lg) ^ (Ln & 7);
    offB[n] = TM * 32 + Ln * 64 + p * 8;
  }

  f32x4 acc[MR][NR] = {};
  constexpr int L = LA + LB;

  for (int tile = 0; tile < nt; ++tile) {
    const int rem = nt - 1 - tile;
    if (rem >= 2)      asm volatile("s_waitcnt vmcnt(%0)" :: "i"(2 * L) : "memory");
    else if (rem == 1) asm volatile("s_waitcnt vmcnt(%0)" :: "i"(L) : "memory");
    else               asm volatile("s_waitcnt vmcnt(0)" ::: "memory");
    __builtin_amdgcn_s_barrier();
    if (tile + 3 < nt) stage(tile + 3);
    const unsigned short* bb = &lds[(tile & (NBUF - 1)) * BUFU];
    bf16x8 af[MR], bf[NR];
#pragma unroll
    for (int m = 0; m < MR; ++m)
      af[m] = *reinterpret_cast<const bf16x8*>(&bb[offA[m]]);
#pragma unroll
    for (int n = 0; n < NR; ++n)
      bf[n] = *reinterpret_cast<const bf16x8*>(&bb[offB[n]]);
    asm volatile("s_waitcnt lgkmcnt(0)" ::: "memory");
    __builtin_amdgcn_sched_barrier(0);
    __builtin_amdgcn_s_setprio(1);
#pragma unroll
    for (int m = 0; m < MR; ++m)
#pragma unroll
      for (int n = 0; n < NR; ++n)
        acc[m][n] = __builtin_amdgcn_mfma_f32_16x16x32_bf16(af[m], bf[n], acc[m][n], 0, 0, 0);
    __builtin_amdgcn_s_setprio(0);
    __builtin_amdgcn_sched_barrier(0);
  }

  const int rbase = m0 + wm * (TM / 2) + lg * 4;
  const int cbase = n0 + wn * (TN / 4) + ln;
#pragma unroll
  for (int m = 0; m < MR; ++m) {
#pragma unroll
    for (int n = 0; n < NR; ++n) {
      int col = cbase + n * 16;
#pragma unroll
      for (int j = 0; j < 4; ++j) {
        int row = rbase + m * 16 + j;
        outF[(size_t)row * N + col] = acc[m][n][j] + resid[(size_t)row * N + col];
      }
    }
  }
}

// ---------------- Flash attention (causal, swapped-QK^T, in-lane softmax) ----
__global__ __launch_bounds__(512) void attn_kernel(
    const unsigned short* __restrict__ qg, const unsigned short* __restrict__ kg,
    const unsigned short* __restrict__ vt, unsigned short* __restrict__ og) {
  __shared__ __attribute__((aligned(16))) unsigned short Kl[64 * 64];
  __shared__ __attribute__((aligned(16))) unsigned short Vl[64 * 64];
  __shared__ __attribute__((aligned(16))) unsigned short Pl[8][16 * 64];
  const int t = threadIdx.x, lane = t & 63, w = t >> 6;
  const int lg = lane >> 4, ln = lane & 15;
  const int bh = blockIdx.y, b = bh >> 4, h = bh & 15;
  const int q0 = ((int)gridDim.x - 1 - (int)blockIdx.x) * 128;
  const int qw = q0 + w * 16;

  bf16x8 aq[2];
  {
    const unsigned short* qp =
        qg + (size_t)(b * S_ + qw + ln) * D_ + h * DK_ + lg * 8;
    aq[0] = *reinterpret_cast<const bf16x8*>(qp);
    aq[1] = *reinterpret_cast<const bf16x8*>(qp + 32);
  }
  float mr = -1e30f, lr = 0.f;
  f32x4 oacc[4] = {};
  const int dqt = qw >> 6;
  const int nt = (q0 >> 6) + 2;
  const float SCL = 0.125f * 1.44269504089f;

  for (int kt = 0; kt < nt; ++kt) {
    const int kv0 = kt * 64;
    {
      int row = t >> 3, cg = t & 7, sg = cg ^ (row & 7);
      gload_lds16(kg + (size_t)(b * S_ + kv0 + row) * D_ + h * DK_ + sg * 8, &Kl[t * 8]);
      gload_lds16(vt + (size_t)(b * D_ + h * DK_ + row) * S_ + kv0 + sg * 8, &Vl[t * 8]);
    }
    __syncthreads();
    if (kt <= dqt) {
      f32x4 sc[4] = {};
#pragma unroll
      for (int n = 0; n < 4; ++n) {
        int r = n * 16 + ln;
#pragma unroll
        for (int c = 0; c < 2; ++c) {
          int cg = (c * 4 + lg) ^ (r & 7);
          bf16x8 bk = *reinterpret_cast<const bf16x8*>(&Kl[r * 64 + cg * 8]);
          sc[n] = __builtin_amdgcn_mfma_f32_16x16x32_bf16(bk, aq[c], sc[n], 0, 0, 0);
        }
      }
      const bool diag = (kt == dqt);
      const int qi = qw + ln;
      float mx = -1e30f;
#pragma unroll
      for (int n = 0; n < 4; ++n)
#pragma unroll
        for (int j = 0; j < 4; ++j) {
          float s = sc[n][j] * SCL;
          if (diag && (kv0 + n * 16 + lg * 4 + j) > qi) s = -1e30f;
          sc[n][j] = s;
          mx = fmaxf(mx, s);
        }
      mx = fmaxf(mx, __shfl_xor(mx, 16));
      mx = fmaxf(mx, __shfl_xor(mx, 32));
      float mn = fmaxf(mr, mx);
      float sf = exp2f(mr - mn);
      mr = mn;
      float ps = 0.f;
#pragma unroll
      for (int n = 0; n < 4; ++n)
#pragma unroll
        for (int j = 0; j < 4; ++j) {
          float p = exp2f(sc[n][j] - mn);
          sc[n][j] = p;
          ps += p;
        }
      ps += __shfl_xor(ps, 16);
      ps += __shfl_xor(ps, 32);
      lr = lr * sf + ps;
#pragma unroll
      for (int j = 0; j < 4; ++j) {
        float sfj = __shfl(sf, lg * 4 + j);
#pragma unroll
        for (int f = 0; f < 4; ++f) oacc[f][j] *= sfj;
      }
      unsigned short* pl = Pl[w];
#pragma unroll
      for (int n = 0; n < 4; ++n) {
        int kvc = n * 16 + lg * 4;
        int cg = (kvc >> 3) ^ (ln & 7);
        unsigned short* dst = &pl[ln * 64 + cg * 8 + (kvc & 7)];
        unsigned p01 = (unsigned)bf16r(sc[n][0]) | ((unsigned)bf16r(sc[n][1]) << 16);
        unsigned p23 = (unsigned)bf16r(sc[n][2]) | ((unsigned)bf16r(sc[n][3]) << 16);
        *reinterpret_cast<unsigned*>(dst) = p01;
        *reinterpret_cast<unsigned*>(dst + 2) = p23;
      }
#pragma unroll
      for (int c = 0; c < 2; ++c) {
        int cgp = (c * 4 + lg) ^ (ln & 7);
        bf16x8 pa = *reinterpret_cast<const bf16x8*>(&pl[ln * 64 + cgp * 8]);
#pragma unroll
        for (int f = 0; f < 4; ++f) {
          int dv = f * 16 + ln;
          int cgv = (c * 4 + lg) ^ (dv & 7);
          bf16x8 vb = *reinterpret_cast<const bf16x8*>(&Vl[dv * 64 + cgv * 8]);
          oacc[f] = __builtin_amdgcn_mfma_f32_16x16x32_bf16(pa, vb, oacc[f], 0, 0, 0);
        }
      }
    }
    __syncthreads();
  }
#pragma unroll
  for (int j = 0; j < 4; ++j) {
    float lj = __shfl(lr, lg * 4 + j);
    float inv = 1.0f / lj;
    int row = b * S_ + qw + lg * 4 + j;
#pragma unroll
    for (int f = 0; f < 4; ++f)
      og[(size_t)row * D_ + h * DK_ + f * 16 + ln] = bf16r(oacc[f][j] * inv);
  }
}

// ---------------- launch ----------------
extern "C" void kernel_launch(void* const* d_in, const int* in_sizes, int n_in,
                              void* d_out, int out_size, void* d_ws, size_t ws_size,
                              hipStream_t stream) {
  const float* x  = (const float*)d_in[0];
  const float* wq = (const float*)d_in[1];
  const float* wk = (const float*)d_in[2];
  const float* wv = (const float*)d_in[3];
  const float* wo = (const float*)d_in[4];
  const float* w1 = (const float*)d_in[5];
  const float* w2 = (const float*)d_in[6];
  const float* g1 = (const float*)d_in[7];
  const float* g2 = (const float*)d_in[8];
  float* out = (float*)d_out;

  char* ws = (char*)d_ws;
  const size_t MB = 1024 * 1024;
  unsigned short* wqkv_b = (unsigned short*)(ws + 0 * MB);   // [3072][1024]
  unsigned short* wo_b   = (unsigned short*)(ws + 6 * MB);
  unsigned short* w1_b   = (unsigned short*)(ws + 8 * MB);
  unsigned short* w2_b   = (unsigned short*)(ws + 16 * MB);
  unsigned short* h_b    = (unsigned short*)(ws + 24 * MB);
  unsigned short* q_b    = (unsigned short*)(ws + 32 * MB);
  unsigned short* k_b    = (unsigned short*)(ws + 40 * MB);
  unsigned short* v_b    = (unsigned short*)(ws + 48 * MB);
  unsigned short* vt_b   = (unsigned short*)(ws + 56 * MB);
  unsigned short* o_b    = (unsigned short*)(ws + 48 * MB);  // reuse v_b (dead after vtrans)
  float*          x1     = (float*)(ws + 64 * MB);
  unsigned short* mid    = (unsigned short*)(ws + 80 * MB);

  CvtArgs ca;
  ca.src[0] = wq; ca.dst[0] = wqkv_b;
  ca.src[1] = wk; ca.dst[1] = wqkv_b + (size_t)D_ * D_;
  ca.src[2] = wv; ca.dst[2] = wqkv_b + (size_t)2 * D_ * D_;
  ca.src[3] = wo; ca.dst[3] = wo_b;
  ca.src[4] = w1; ca.dst[4] = w1_b;
  ca.src[5] = w2; ca.dst[5] = w2_b;
  int q4 = D_ * D_ / 4, f4 = F_ * D_ / 4;
  ca.start[0] = 0;
  ca.start[1] = q4;
  ca.start[2] = 2 * q4;
  ca.start[3] = 3 * q4;
  ca.start[4] = 4 * q4;
  ca.start[5] = 4 * q4 + f4;
  ca.start[6] = 4 * q4 + 2 * f4;
  cvt_all_kernel<<<(ca.start[6] + 255) / 256, 256, 0, stream>>>(ca);

  rmsnorm_kernel<<<NTOK, 256, 0, stream>>>(x, g1, h_b);

  // fused QKV: N=3072, direct-register GEMM, grid 24x32
  gemm_reg<0, 5><<<dim3(3 * D_ / 128, NTOK / 128), dim3(256), 0, stream>>>(
      h_b, wqkv_b, NTOK, 3 * D_, D_, q_b, k_b, v_b);

  vtrans_kernel<<<dim3(NTOK / 64, D_ / 64), dim3(256), 0, stream>>>(v_b, vt_b);

  attn_kernel<<<dim3(S_ / 128, B_ * H_), dim3(512), 0, stream>>>(q_b, k_b, vt_b, o_b);

  // WO + residual: N=1024, LDS-pipelined, grid 8x32
  gemm_pipe<1><<<dim3(D_ / 128, NTOK / 128), dim3(512), 0, stream>>>(
      o_b, wo_b, NTOK, D_, D_, x, x1);

  rmsnorm_kernel<<<NTOK, 256, 0, stream>>>(x1, g2, h_b);

  // FFN1 + fast GELU: N=4096, direct-register GEMM, grid 32x32
  gemm_reg<1, 1><<<dim3(F_ / 128, NTOK / 128), dim3(256), 0, stream>>>(
      h_b, w1_b, NTOK, F_, D_, mid, nullptr, nullptr);

  // FFN2 + residual: N=1024, LDS-pipelined, grid 8x32
  gemm_pipe<2><<<dim3(D_ / 128, NTOK / 128), dim3(512), 0, stream>>>(
      mid, w2_b, NTOK, D_, F_, x1, out);
}

// Round 6
// 284.774 us; speedup vs baseline: 1.3965x; 1.3965x over previous
//
#include <hip/hip_runtime.h>
#include <hip/hip_bf16.h>
#include <math.h>

#define B_   2
#define S_   2048
#define D_   1024
#define H_   16
#define DK_  64
#define F_   4096
#define NTOK (B_ * S_)

typedef __bf16 bf16x8 __attribute__((ext_vector_type(8)));
typedef float  f32x4  __attribute__((ext_vector_type(4)));

__device__ __forceinline__ unsigned short bf16r(float f) {
  unsigned u = __builtin_bit_cast(unsigned, f);
  u += 0x7fffu + ((u >> 16) & 1u);
  return (unsigned short)(u >> 16);
}

__device__ __forceinline__ void gload_lds16(const void* g, void* l) {
  __builtin_amdgcn_global_load_lds(
      (__attribute__((address_space(1))) void*)g,
      (__attribute__((address_space(3))) void*)l, 16, 0, 0);
}

// tanh-form GELU via exp2 (max abs err ~3e-3; validated round 5, absmax unchanged)
__device__ __forceinline__ float gelu_fast(float x) {
  float y = 0.7978845608f * x * (1.0f + 0.044715f * x * x);
  float e = exp2f(2.885390082f * y);  // e^(2y)
  float t = 1.0f - 2.0f / (e + 1.0f);
  return 0.5f * x * (1.0f + t);
}

// ---------------- all weights fp32 -> bf16, one launch ----------------
struct CvtArgs {
  const float* src[6];
  unsigned short* dst[6];
  int start[7];
};
__global__ __launch_bounds__(256) void cvt_all_kernel(CvtArgs a) {
  int i = blockIdx.x * blockDim.x + threadIdx.x;  // float4 chunk index
  if (i >= a.start[6]) return;
  int k = 0;
#pragma unroll
  for (int j = 1; j < 6; ++j)
    if (i >= a.start[j]) k = j;
  int off = i - a.start[k];
  float4 v = reinterpret_cast<const float4*>(a.src[k])[off];
  ushort4 o;
  o.x = bf16r(v.x); o.y = bf16r(v.y); o.z = bf16r(v.z); o.w = bf16r(v.w);
  reinterpret_cast<ushort4*>(a.dst[k])[off] = o;
}

// ---------------- RMSNorm (fp32 in, bf16 out) ----------------
__global__ __launch_bounds__(256) void rmsnorm_kernel(
    const float* __restrict__ x, const float* __restrict__ g,
    unsigned short* __restrict__ out) {
  int row = blockIdx.x;
  int t = threadIdx.x, lane = t & 63, w = t >> 6;
  float4 v = reinterpret_cast<const float4*>(x + (size_t)row * D_)[t];
  float ss = v.x * v.x + v.y * v.y + v.z * v.z + v.w * v.w;
#pragma unroll
  for (int d = 1; d < 64; d <<= 1) ss += __shfl_xor(ss, d);
  __shared__ float red[4];
  if (lane == 0) red[w] = ss;
  __syncthreads();
  float tot = red[0] + red[1] + red[2] + red[3];
  float rstd = rsqrtf(tot * (1.0f / D_) + 1e-5f);
  float4 gv = reinterpret_cast<const float4*>(g)[t];
  ushort4 o;
  o.x = bf16r(v.x * rstd * gv.x);
  o.y = bf16r(v.y * rstd * gv.y);
  o.z = bf16r(v.z * rstd * gv.z);
  o.w = bf16r(v.w * rstd * gv.w);
  reinterpret_cast<ushort4*>(out + (size_t)row * D_)[t] = o;
}

// ======== 256x256 phase-scheduled GEMM body (BK=32, 4-buf ring) =============
// Per phase: {ds_read frags, stage half of t+3, barrier, setprio(1), 16 MFMA,
// setprio(0), barrier}. One BARE counted vmcnt per K-tile (never clobbered asm:
// a "memory" clobber makes SIInsertWaitcnts prepend vmcnt(0) -> full drain).
// EPI 1: fast-GELU->bf16 | 4: QKV scatter (q, k, v^T)
template <int EPI>
__device__ __forceinline__ void gemm256_body(
    const unsigned short* __restrict__ A, const unsigned short* __restrict__ Bw,
    int M, int N, int K,
    unsigned short* __restrict__ outB, unsigned short* __restrict__ outB2,
    unsigned short* __restrict__ outB3) {
  __shared__ __attribute__((aligned(16))) unsigned short lds[65536];  // 128 KB
  const int t = threadIdx.x, lane = t & 63, w = t >> 6;
  const int wm = w >> 2, wn = w & 3;
  const int lg = lane >> 4, ln = lane & 15;

  // bijective XCD-aware remap (nwg % 8 == 0 for all our grids)
  const int gx = gridDim.x;
  int bid = blockIdx.y * gx + blockIdx.x;
  int xcd = bid & 7, c = bid >> 3;
  int RX = gx >> 2, RY = gridDim.y >> 1;
  int bx = (xcd & 3) * RX + (c % RX);
  int by = (xcd >> 2) * RY + (c / RX);
  const int m0 = by * 256, n0 = bx * 256;

  const int nt = K >> 5;

  auto stageA = [&](int tile) {
    unsigned short* la = &lds[(tile & 3) * 16384];
    const int k0 = tile << 5;
#pragma unroll
    for (int i = 0; i < 2; ++i) {
      int g = i * 512 + t;
      int Ln = g >> 3, p = g & 7, u = p ^ (Ln & 7);
      int row = 2 * Ln + (u >> 2), cg = u & 3;
      gload_lds16(A + (size_t)(m0 + row) * K + k0 + cg * 8, &la[g * 8]);
    }
  };
  auto stageB = [&](int tile) {
    unsigned short* lb = &lds[(tile & 3) * 16384 + 8192];
    const int k0 = tile << 5;
#pragma unroll
    for (int i = 0; i < 2; ++i) {
      int g = i * 512 + t;
      int Ln = g >> 3, p = g & 7, u = p ^ (Ln & 7);
      int row = 2 * Ln + (u >> 2), cg = u & 3;
      gload_lds16(Bw + (size_t)(n0 + row) * K + k0 + cg * 8, &lb[g * 8]);
    }
  };

  stageA(0); stageB(0);
  stageA(1); stageB(1);
  stageA(2); stageB(2);

  // swizzled fragment offsets (ushort index within a buffer)
  int offA[8], offB[4];
#pragma unroll
  for (int m = 0; m < 8; ++m) {
    int r = wm * 128 + m * 16 + ln;
    int Ln = r >> 1, p = ((r & 1) * 4 + lg) ^ (Ln & 7);
    offA[m] = Ln * 64 + p * 8;
  }
#pragma unroll
  for (int n = 0; n < 4; ++n) {
    int r = wn * 64 + n * 16 + ln;
    int Ln = r >> 1, p = ((r & 1) * 4 + lg) ^ (Ln & 7);
    offB[n] = 8192 + Ln * 64 + p * 8;
  }

  f32x4 acc[8][4] = {};

  asm volatile("s_waitcnt vmcnt(8)");  // bare: tile 0 landed
  __builtin_amdgcn_sched_barrier(0);
  __builtin_amdgcn_s_barrier();

  for (int tile = 0; tile < nt; ++tile) {
    const unsigned short* base = &lds[(tile & 3) * 16384];
    bf16x8 af[4], bf[4], af2[4];
    // ---- phase 1: m-frags 0..3 x n-frags 0..3 ----
#pragma unroll
    for (int m = 0; m < 4; ++m)
      af[m] = *reinterpret_cast<const bf16x8*>(&base[offA[m]]);
#pragma unroll
    for (int n = 0; n < 4; ++n)
      bf[n] = *reinterpret_cast<const bf16x8*>(&base[offB[n]]);
    if (tile + 3 < nt) stageA(tile + 3);
    __builtin_amdgcn_s_barrier();
    __builtin_amdgcn_s_setprio(1);
#pragma unroll
    for (int m = 0; m < 4; ++m)
#pragma unroll
      for (int n = 0; n < 4; ++n)
        acc[m][n] = __builtin_amdgcn_mfma_f32_16x16x32_bf16(af[m], bf[n], acc[m][n], 0, 0, 0);
    __builtin_amdgcn_s_setprio(0);
    __builtin_amdgcn_s_barrier();
    // ---- phase 2: m-frags 4..7 x n-frags 0..3 ----
#pragma unroll
    for (int m = 0; m < 4; ++m)
      af2[m] = *reinterpret_cast<const bf16x8*>(&base[offA[4 + m]]);
    if (tile + 3 < nt) stageB(tile + 3);
    const int rem = nt - 1 - tile;
    if (rem >= 3)      { asm volatile("s_waitcnt vmcnt(8)"); }
    else if (rem == 2) { asm volatile("s_waitcnt vmcnt(4)"); }
    else if (rem == 1) { asm volatile("s_waitcnt vmcnt(0)"); }
    __builtin_amdgcn_sched_barrier(0);
    __builtin_amdgcn_s_barrier();
    __builtin_amdgcn_s_setprio(1);
#pragma unroll
    for (int m = 0; m < 4; ++m)
#pragma unroll
      for (int n = 0; n < 4; ++n)
        acc[4 + m][n] = __builtin_amdgcn_mfma_f32_16x16x32_bf16(af2[m], bf[n], acc[4 + m][n], 0, 0, 0);
    __builtin_amdgcn_s_setprio(0);
    __builtin_amdgcn_s_barrier();
  }

  const int rbase = m0 + wm * 128 + lg * 4;
  const int cbase = n0 + wn * 64 + ln;
#pragma unroll
  for (int m = 0; m < 8; ++m) {
#pragma unroll
    for (int n = 0; n < 4; ++n) {
      int col = cbase + n * 16;
#pragma unroll
      for (int j = 0; j < 4; ++j) {
        int row = rbase + m * 16 + j;
        float v = acc[m][n][j];
        if (EPI == 1) {
          outB[(size_t)row * N + col] = bf16r(gelu_fast(v));
        } else {  // EPI 4: QKV scatter
          if (col < D_) {
            outB[(size_t)row * D_ + col] = bf16r(v);
          } else if (col < 2 * D_) {
            outB2[(size_t)row * D_ + (col - D_)] = bf16r(v);
          } else {
            int bb2 = row >> 11, s = row & (S_ - 1);
            outB3[((size_t)(bb2 * D_) + (col - 2 * D_)) * S_ + s] = bf16r(v);
          }
        }
      }
    }
  }
}

__global__ __launch_bounds__(512, 2) void qkv_gemm256(
    const unsigned short* __restrict__ A, const unsigned short* __restrict__ Bw,
    int M, int N, int K, unsigned short* o1, unsigned short* o2, unsigned short* o3) {
  gemm256_body<4>(A, Bw, M, N, K, o1, o2, o3);
}
__global__ __launch_bounds__(512, 2) void ffn1_gemm256(
    const unsigned short* __restrict__ A, const unsigned short* __restrict__ Bw,
    int M, int N, int K, unsigned short* o1, unsigned short* o2, unsigned short* o3) {
  gemm256_body<1>(A, Bw, M, N, K, o1, o2, o3);
}

// ---------------- 128x128 pipelined GEMM body (4-deep) for N=1024 outputs ---
// +resid -> fp32 epilogue. Bare counted vmcnt (no clobbers).
__device__ __forceinline__ void gemm128_body(
    const unsigned short* __restrict__ A, const unsigned short* __restrict__ Bw,
    int M, int N, int K,
    const float* __restrict__ resid, float* __restrict__ outF) {
  constexpr int TM = 128, TN = 128;
  constexpr int NBUF = 4;
  constexpr int MR = 4, NR = 2;
  constexpr int LA = 1, LB = 1;
  constexpr int BUFU = (TM + TN) * 32;
  __shared__ __attribute__((aligned(16))) unsigned short lds[NBUF * BUFU];

  const int t = threadIdx.x, lane = t & 63, w = t >> 6;
  const int wm = w >> 2, wn = w & 3;
  const int lg = lane >> 4, ln = lane & 15;

  const int gx = gridDim.x;
  int bid = blockIdx.y * gx + blockIdx.x;
  int RX = gx >> 2, RY = gridDim.y >> 1;
  int xcd = bid & 7, c = bid >> 3;
  int bx = (xcd & 3) * RX + (c % RX);
  int by = (xcd >> 2) * RY + (c / RX);
  const int m0 = by * TM, n0 = bx * TN;

  const int nt = K >> 5;

  auto stage = [&](int tile) {
    const int buf = tile & (NBUF - 1);
    const int k0 = tile << 5;
    unsigned short* la = &lds[buf * BUFU];
    unsigned short* lb = la + TM * 32;
    {
      int g = t;
      int Ln = g >> 3, p = g & 7, u = p ^ (Ln & 7);
      int row = 2 * Ln + (u >> 2), cg = u & 3;
      gload_lds16(A + (size_t)(m0 + row) * K + k0 + cg * 8, &la[g * 8]);
      gload_lds16(Bw + (size_t)(n0 + row) * K + k0 + cg * 8, &lb[g * 8]);
    }
  };

  stage(0);
  if (nt > 1) stage(1);
  if (nt > 2) stage(2);

  int offA[MR], offB[NR];
#pragma unroll
  for (int m = 0; m < MR; ++m) {
    int r = wm * (TM / 2) + m * 16 + ln;
    int Ln = r >> 1, p = ((r & 1) * 4 + lg) ^ (Ln & 7);
    offA[m] = Ln * 64 + p * 8;
  }
#pragma unroll
  for (int n = 0; n < NR; ++n) {
    int r = wn * (TN / 4) + n * 16 + ln;
    int Ln = r >> 1, p = ((r & 1) * 4 + lg) ^ (Ln & 7);
    offB[n] = TM * 32 + Ln * 64 + p * 8;
  }

  f32x4 acc[MR][NR] = {};

  for (int tile = 0; tile < nt; ++tile) {
    const int rem = nt - 1 - tile;
    if (rem >= 2)      { asm volatile("s_waitcnt vmcnt(4)"); }
    else if (rem == 1) { asm volatile("s_waitcnt vmcnt(2)"); }
    else               { asm volatile("s_waitcnt vmcnt(0)"); }
    __builtin_amdgcn_sched_barrier(0);
    __builtin_amdgcn_s_barrier();
    if (tile + 3 < nt) stage(tile + 3);
    const unsigned short* bb = &lds[(tile & (NBUF - 1)) * BUFU];
    bf16x8 af[MR], bf[NR];
#pragma unroll
    for (int m = 0; m < MR; ++m)
      af[m] = *reinterpret_cast<const bf16x8*>(&bb[offA[m]]);
#pragma unroll
    for (int n = 0; n < NR; ++n)
      bf[n] = *reinterpret_cast<const bf16x8*>(&bb[offB[n]]);
    __builtin_amdgcn_s_setprio(1);
#pragma unroll
    for (int m = 0; m < MR; ++m)
#pragma unroll
      for (int n = 0; n < NR; ++n)
        acc[m][n] = __builtin_amdgcn_mfma_f32_16x16x32_bf16(af[m], bf[n], acc[m][n], 0, 0, 0);
    __builtin_amdgcn_s_setprio(0);
  }

  const int rbase = m0 + wm * (TM / 2) + lg * 4;
  const int cbase = n0 + wn * (TN / 4) + ln;
#pragma unroll
  for (int m = 0; m < MR; ++m) {
#pragma unroll
    for (int n = 0; n < NR; ++n) {
      int col = cbase + n * 16;
#pragma unroll
      for (int j = 0; j < 4; ++j) {
        int row = rbase + m * 16 + j;
        outF[(size_t)row * N + col] = acc[m][n][j] + resid[(size_t)row * N + col];
      }
    }
  }
}

__global__ __launch_bounds__(512, 4) void wo_gemm128(
    const unsigned short* __restrict__ A, const unsigned short* __restrict__ Bw,
    int M, int N, int K, const float* __restrict__ resid, float* __restrict__ outF) {
  gemm128_body(A, Bw, M, N, K, resid, outF);
}
__global__ __launch_bounds__(512, 4) void ffn2_gemm128(
    const unsigned short* __restrict__ A, const unsigned short* __restrict__ Bw,
    int M, int N, int K, const float* __restrict__ resid, float* __restrict__ outF) {
  gemm128_body(A, Bw, M, N, K, resid, outF);
}

// ---------------- Flash attention (causal, swapped-QK^T, in-lane softmax) ----
__global__ __launch_bounds__(512) void attn_kernel(
    const unsigned short* __restrict__ qg, const unsigned short* __restrict__ kg,
    const unsigned short* __restrict__ vt, unsigned short* __restrict__ og) {
  __shared__ __attribute__((aligned(16))) unsigned short Kl[64 * 64];
  __shared__ __attribute__((aligned(16))) unsigned short Vl[64 * 64];
  __shared__ __attribute__((aligned(16))) unsigned short Pl[8][16 * 64];
  const int t = threadIdx.x, lane = t & 63, w = t >> 6;
  const int lg = lane >> 4, ln = lane & 15;
  const int bh = blockIdx.y, b = bh >> 4, h = bh & 15;
  const int q0 = ((int)gridDim.x - 1 - (int)blockIdx.x) * 128;
  const int qw = q0 + w * 16;

  bf16x8 aq[2];
  {
    const unsigned short* qp =
        qg + (size_t)(b * S_ + qw + ln) * D_ + h * DK_ + lg * 8;
    aq[0] = *reinterpret_cast<const bf16x8*>(qp);
    aq[1] = *reinterpret_cast<const bf16x8*>(qp + 32);
  }
  float mr = -1e30f, lr = 0.f;
  f32x4 oacc[4] = {};
  const int dqt = qw >> 6;
  const int nt = (q0 >> 6) + 2;
  const float SCL = 0.125f * 1.44269504089f;

  for (int kt = 0; kt < nt; ++kt) {
    const int kv0 = kt * 64;
    {
      int row = t >> 3, cg = t & 7, sg = cg ^ (row & 7);
      gload_lds16(kg + (size_t)(b * S_ + kv0 + row) * D_ + h * DK_ + sg * 8, &Kl[t * 8]);
      gload_lds16(vt + (size_t)(b * D_ + h * DK_ + row) * S_ + kv0 + sg * 8, &Vl[t * 8]);
    }
    __syncthreads();
    if (kt <= dqt) {
      f32x4 sc[4] = {};
#pragma unroll
      for (int n = 0; n < 4; ++n) {
        int r = n * 16 + ln;
#pragma unroll
        for (int c = 0; c < 2; ++c) {
          int cg = (c * 4 + lg) ^ (r & 7);
          bf16x8 bk = *reinterpret_cast<const bf16x8*>(&Kl[r * 64 + cg * 8]);
          sc[n] = __builtin_amdgcn_mfma_f32_16x16x32_bf16(bk, aq[c], sc[n], 0, 0, 0);
        }
      }
      const bool diag = (kt == dqt);
      const int qi = qw + ln;
      float mx = -1e30f;
#pragma unroll
      for (int n = 0; n < 4; ++n)
#pragma unroll
        for (int j = 0; j < 4; ++j) {
          float s = sc[n][j] * SCL;
          if (diag && (kv0 + n * 16 + lg * 4 + j) > qi) s = -1e30f;
          sc[n][j] = s;
          mx = fmaxf(mx, s);
        }
      mx = fmaxf(mx, __shfl_xor(mx, 16));
      mx = fmaxf(mx, __shfl_xor(mx, 32));
      float mn = fmaxf(mr, mx);
      float sf = exp2f(mr - mn);
      mr = mn;
      float ps = 0.f;
#pragma unroll
      for (int n = 0; n < 4; ++n)
#pragma unroll
        for (int j = 0; j < 4; ++j) {
          float p = exp2f(sc[n][j] - mn);
          sc[n][j] = p;
          ps += p;
        }
      ps += __shfl_xor(ps, 16);
      ps += __shfl_xor(ps, 32);
      lr = lr * sf + ps;
#pragma unroll
      for (int j = 0; j < 4; ++j) {
        float sfj = __shfl(sf, lg * 4 + j);
#pragma unroll
        for (int f = 0; f < 4; ++f) oacc[f][j] *= sfj;
      }
      unsigned short* pl = Pl[w];
#pragma unroll
      for (int n = 0; n < 4; ++n) {
        int kvc = n * 16 + lg * 4;
        int cg = (kvc >> 3) ^ (ln & 7);
        unsigned short* dst = &pl[ln * 64 + cg * 8 + (kvc & 7)];
        unsigned p01 = (unsigned)bf16r(sc[n][0]) | ((unsigned)bf16r(sc[n][1]) << 16);
        unsigned p23 = (unsigned)bf16r(sc[n][2]) | ((unsigned)bf16r(sc[n][3]) << 16);
        *reinterpret_cast<unsigned*>(dst) = p01;
        *reinterpret_cast<unsigned*>(dst + 2) = p23;
      }
#pragma unroll
      for (int c = 0; c < 2; ++c) {
        int cgp = (c * 4 + lg) ^ (ln & 7);
        bf16x8 pa = *reinterpret_cast<const bf16x8*>(&pl[ln * 64 + cgp * 8]);
#pragma unroll
        for (int f = 0; f < 4; ++f) {
          int dv = f * 16 + ln;
          int cgv = (c * 4 + lg) ^ (dv & 7);
          bf16x8 vb = *reinterpret_cast<const bf16x8*>(&Vl[dv * 64 + cgv * 8]);
          oacc[f] = __builtin_amdgcn_mfma_f32_16x16x32_bf16(pa, vb, oacc[f], 0, 0, 0);
        }
      }
    }
    __syncthreads();
  }
#pragma unroll
  for (int j = 0; j < 4; ++j) {
    float lj = __shfl(lr, lg * 4 + j);
    float inv = 1.0f / lj;
    int row = b * S_ + qw + lg * 4 + j;
#pragma unroll
    for (int f = 0; f < 4; ++f)
      og[(size_t)row * D_ + h * DK_ + f * 16 + ln] = bf16r(oacc[f][j] * inv);
  }
}

// ---------------- launch ----------------
extern "C" void kernel_launch(void* const* d_in, const int* in_sizes, int n_in,
                              void* d_out, int out_size, void* d_ws, size_t ws_size,
                              hipStream_t stream) {
  const float* x  = (const float*)d_in[0];
  const float* wq = (const float*)d_in[1];
  const float* wk = (const float*)d_in[2];
  const float* wv = (const float*)d_in[3];
  const float* wo = (const float*)d_in[4];
  const float* w1 = (const float*)d_in[5];
  const float* w2 = (const float*)d_in[6];
  const float* g1 = (const float*)d_in[7];
  const float* g2 = (const float*)d_in[8];
  float* out = (float*)d_out;

  char* ws = (char*)d_ws;
  const size_t MB = 1024 * 1024;
  unsigned short* wqkv_b = (unsigned short*)(ws + 0 * MB);   // [3072][1024]
  unsigned short* wo_b   = (unsigned short*)(ws + 6 * MB);
  unsigned short* w1_b   = (unsigned short*)(ws + 8 * MB);
  unsigned short* w2_b   = (unsigned short*)(ws + 16 * MB);
  unsigned short* h_b    = (unsigned short*)(ws + 24 * MB);
  unsigned short* q_b    = (unsigned short*)(ws + 32 * MB);
  unsigned short* k_b    = (unsigned short*)(ws + 40 * MB);
  unsigned short* vt_b   = (unsigned short*)(ws + 48 * MB);
  unsigned short* o_b    = (unsigned short*)(ws + 56 * MB);
  float*          x1     = (float*)(ws + 64 * MB);
  unsigned short* mid    = (unsigned short*)(ws + 80 * MB);

  CvtArgs ca;
  ca.src[0] = wq; ca.dst[0] = wqkv_b;
  ca.src[1] = wk; ca.dst[1] = wqkv_b + (size_t)D_ * D_;
  ca.src[2] = wv; ca.dst[2] = wqkv_b + (size_t)2 * D_ * D_;
  ca.src[3] = wo; ca.dst[3] = wo_b;
  ca.src[4] = w1; ca.dst[4] = w1_b;
  ca.src[5] = w2; ca.dst[5] = w2_b;
  int q4 = D_ * D_ / 4, f4 = F_ * D_ / 4;
  ca.start[0] = 0;
  ca.start[1] = q4;
  ca.start[2] = 2 * q4;
  ca.start[3] = 3 * q4;
  ca.start[4] = 4 * q4;
  ca.start[5] = 4 * q4 + f4;
  ca.start[6] = 4 * q4 + 2 * f4;
  cvt_all_kernel<<<(ca.start[6] + 255) / 256, 256, 0, stream>>>(ca);

  rmsnorm_kernel<<<NTOK, 256, 0, stream>>>(x, g1, h_b);

  // fused QKV: N=3072, 256^2 phase-scheduled, grid 12x16
  qkv_gemm256<<<dim3(3 * D_ / 256, NTOK / 256), dim3(512), 0, stream>>>(
      h_b, wqkv_b, NTOK, 3 * D_, D_, q_b, k_b, vt_b);

  attn_kernel<<<dim3(S_ / 128, B_ * H_), dim3(512), 0, stream>>>(q_b, k_b, vt_b, o_b);

  // WO + residual: N=1024, 128^2 4-deep, grid 8x32
  wo_gemm128<<<dim3(D_ / 128, NTOK / 128), dim3(512), 0, stream>>>(
      o_b, wo_b, NTOK, D_, D_, x, x1);

  rmsnorm_kernel<<<NTOK, 256, 0, stream>>>(x1, g2, h_b);

  // FFN1 + fast GELU: N=4096, 256^2 phase-scheduled, grid 16x16
  ffn1_gemm256<<<dim3(F_ / 256, NTOK / 256), dim3(512), 0, stream>>>(
      h_b, w1_b, NTOK, F_, D_, mid, nullptr, nullptr);

  // FFN2 + residual: N=1024, 128^2 4-deep, grid 8x32
  ffn2_gemm128<<<dim3(D_ / 128, NTOK / 128), dim3(512), 0, stream>>>(
      mid, w2_b, NTOK, D_, F_, x1, out);
}

// Round 7
// 279.925 us; speedup vs baseline: 1.4207x; 1.0173x over previous
//
#include <hip/hip_runtime.h>
#include <hip/hip_bf16.h>
#include <math.h>

#define B_   2
#define S_   2048
#define D_   1024
#define H_   16
#define DK_  64
#define F_   4096
#define NTOK (B_ * S_)

typedef __bf16 bf16x8 __attribute__((ext_vector_type(8)));
typedef float  f32x4  __attribute__((ext_vector_type(4)));

__device__ __forceinline__ unsigned short bf16r(float f) {
  unsigned u = __builtin_bit_cast(unsigned, f);
  u += 0x7fffu + ((u >> 16) & 1u);
  return (unsigned short)(u >> 16);
}

__device__ __forceinline__ void gload_lds16(const void* g, void* l) {
  __builtin_amdgcn_global_load_lds(
      (__attribute__((address_space(1))) void*)g,
      (__attribute__((address_space(3))) void*)l, 16, 0, 0);
}

// tanh-form GELU via exp2 (max abs err ~3e-3; validated rounds 5-6)
__device__ __forceinline__ float gelu_fast(float x) {
  float y = 0.7978845608f * x * (1.0f + 0.044715f * x * x);
  float e = exp2f(2.885390082f * y);  // e^(2y)
  float t = 1.0f - 2.0f / (e + 1.0f);
  return 0.5f * x * (1.0f + t);
}

// ---------------- all weights fp32 -> bf16, one launch ----------------
struct CvtArgs {
  const float* src[6];
  unsigned short* dst[6];
  int start[7];
};
__global__ __launch_bounds__(256) void cvt_all_kernel(CvtArgs a) {
  int i = blockIdx.x * blockDim.x + threadIdx.x;  // float4 chunk index
  if (i >= a.start[6]) return;
  int k = 0;
#pragma unroll
  for (int j = 1; j < 6; ++j)
    if (i >= a.start[j]) k = j;
  int off = i - a.start[k];
  float4 v = reinterpret_cast<const float4*>(a.src[k])[off];
  ushort4 o;
  o.x = bf16r(v.x); o.y = bf16r(v.y); o.z = bf16r(v.z); o.w = bf16r(v.w);
  reinterpret_cast<ushort4*>(a.dst[k])[off] = o;
}

// ---------------- RMSNorm (fp32 in, bf16 out) ----------------
__global__ __launch_bounds__(256) void rmsnorm_kernel(
    const float* __restrict__ x, const float* __restrict__ g,
    unsigned short* __restrict__ out) {
  int row = blockIdx.x;
  int t = threadIdx.x, lane = t & 63, w = t >> 6;
  float4 v = reinterpret_cast<const float4*>(x + (size_t)row * D_)[t];
  float ss = v.x * v.x + v.y * v.y + v.z * v.z + v.w * v.w;
#pragma unroll
  for (int d = 1; d < 64; d <<= 1) ss += __shfl_xor(ss, d);
  __shared__ float red[4];
  if (lane == 0) red[w] = ss;
  __syncthreads();
  float tot = red[0] + red[1] + red[2] + red[3];
  float rstd = rsqrtf(tot * (1.0f / D_) + 1e-5f);
  float4 gv = reinterpret_cast<const float4*>(g)[t];
  ushort4 o;
  o.x = bf16r(v.x * rstd * gv.x);
  o.y = bf16r(v.y * rstd * gv.y);
  o.z = bf16r(v.z * rstd * gv.z);
  o.w = bf16r(v.w * rstd * gv.w);
  reinterpret_cast<ushort4*>(out + (size_t)row * D_)[t] = o;
}

// ======== 128x128 4-deep pipelined GEMM body (BK=32, bare counted vmcnt) ====
// 512 thr / 8 waves (2M x 4N), per-wave 64x32 out (4x2 frags). 64 KB LDS ->
// 2 blocks/CU (cross-block latency hiding). Paired-line XOR swizzle, verified
// 0 bank conflicts. EPI 1: GELU->bf16 | 2: +resid->fp32 | 4: QKV scatter.
template <int EPI>
__device__ __forceinline__ void gemm128_body(
    const unsigned short* __restrict__ A, const unsigned short* __restrict__ Bw,
    int M, int N, int K,
    const float* __restrict__ resid, float* __restrict__ outF,
    unsigned short* __restrict__ outB, unsigned short* __restrict__ outB2,
    unsigned short* __restrict__ outB3) {
  constexpr int TM = 128, TN = 128;
  constexpr int NBUF = 4;
  constexpr int MR = 4, NR = 2;
  constexpr int BUFU = (TM + TN) * 32;
  __shared__ __attribute__((aligned(16))) unsigned short lds[NBUF * BUFU];

  const int t = threadIdx.x, lane = t & 63, w = t >> 6;
  const int wm = w >> 2, wn = w & 3;
  const int lg = lane >> 4, ln = lane & 15;

  // bijective XCD-aware remap (all grids: gx%4==0, gy%2==0, nwg%8==0)
  const int gx = gridDim.x;
  int bid = blockIdx.y * gx + blockIdx.x;
  int RX = gx >> 2, RY = gridDim.y >> 1;
  int xcd = bid & 7, c = bid >> 3;
  int bx = (xcd & 3) * RX + (c % RX);
  int by = (xcd >> 2) * RY + (c / RX);
  const int m0 = by * TM, n0 = bx * TN;

  const int nt = K >> 5;

  auto stage = [&](int tile) {
    const int buf = tile & (NBUF - 1);
    const int k0 = tile << 5;
    unsigned short* la = &lds[buf * BUFU];
    unsigned short* lb = la + TM * 32;
    int g = t;
    int Ln = g >> 3, p = g & 7, u = p ^ (Ln & 7);
    int row = 2 * Ln + (u >> 2), cg = u & 3;
    gload_lds16(A + (size_t)(m0 + row) * K + k0 + cg * 8, &la[g * 8]);
    gload_lds16(Bw + (size_t)(n0 + row) * K + k0 + cg * 8, &lb[g * 8]);
  };

  stage(0);
  if (nt > 1) stage(1);
  if (nt > 2) stage(2);

  int offA[MR], offB[NR];
#pragma unroll
  for (int m = 0; m < MR; ++m) {
    int r = wm * (TM / 2) + m * 16 + ln;
    int Ln = r >> 1, p = ((r & 1) * 4 + lg) ^ (Ln & 7);
    offA[m] = Ln * 64 + p * 8;
  }
#pragma unroll
  for (int n = 0; n < NR; ++n) {
    int r = wn * (TN / 4) + n * 16 + ln;
    int Ln = r >> 1, p = ((r & 1) * 4 + lg) ^ (Ln & 7);
    offB[n] = TM * 32 + Ln * 64 + p * 8;
  }

  f32x4 acc[MR][NR] = {};

  for (int tile = 0; tile < nt; ++tile) {
    const int rem = nt - 1 - tile;
    if (rem >= 2)      { asm volatile("s_waitcnt vmcnt(4)"); }
    else if (rem == 1) { asm volatile("s_waitcnt vmcnt(2)"); }
    else               { asm volatile("s_waitcnt vmcnt(0)"); }
    __builtin_amdgcn_sched_barrier(0);
    __builtin_amdgcn_s_barrier();
    if (tile + 3 < nt) stage(tile + 3);
    const unsigned short* bb = &lds[(tile & (NBUF - 1)) * BUFU];
    bf16x8 af[MR], bf[NR];
#pragma unroll
    for (int m = 0; m < MR; ++m)
      af[m] = *reinterpret_cast<const bf16x8*>(&bb[offA[m]]);
#pragma unroll
    for (int n = 0; n < NR; ++n)
      bf[n] = *reinterpret_cast<const bf16x8*>(&bb[offB[n]]);
    __builtin_amdgcn_s_setprio(1);
#pragma unroll
    for (int m = 0; m < MR; ++m)
#pragma unroll
      for (int n = 0; n < NR; ++n)
        acc[m][n] = __builtin_amdgcn_mfma_f32_16x16x32_bf16(af[m], bf[n], acc[m][n], 0, 0, 0);
    __builtin_amdgcn_s_setprio(0);
  }

  const int rbase = m0 + wm * (TM / 2) + lg * 4;
  const int cbase = n0 + wn * (TN / 4) + ln;
#pragma unroll
  for (int m = 0; m < MR; ++m) {
#pragma unroll
    for (int n = 0; n < NR; ++n) {
      int col = cbase + n * 16;
#pragma unroll
      for (int j = 0; j < 4; ++j) {
        int row = rbase + m * 16 + j;
        float v = acc[m][n][j];
        if (EPI == 1) {
          outB[(size_t)row * N + col] = bf16r(gelu_fast(v));
        } else if (EPI == 2) {
          outF[(size_t)row * N + col] = v + resid[(size_t)row * N + col];
        } else {  // EPI 4: QKV scatter (q, k row-major; v transposed)
          if (col < D_) {
            outB[(size_t)row * D_ + col] = bf16r(v);
          } else if (col < 2 * D_) {
            outB2[(size_t)row * D_ + (col - D_)] = bf16r(v);
          } else {
            int bb2 = row >> 11, s = row & (S_ - 1);
            outB3[((size_t)(bb2 * D_) + (col - 2 * D_)) * S_ + s] = bf16r(v);
          }
        }
      }
    }
  }
}

__global__ __launch_bounds__(512, 4) void qkv_gemm(
    const unsigned short* __restrict__ A, const unsigned short* __restrict__ Bw,
    int M, int N, int K, unsigned short* o1, unsigned short* o2, unsigned short* o3) {
  gemm128_body<4>(A, Bw, M, N, K, nullptr, nullptr, o1, o2, o3);
}
__global__ __launch_bounds__(512, 4) void ffn1_gemm(
    const unsigned short* __restrict__ A, const unsigned short* __restrict__ Bw,
    int M, int N, int K, unsigned short* o1) {
  gemm128_body<1>(A, Bw, M, N, K, nullptr, nullptr, o1, nullptr, nullptr);
}
__global__ __launch_bounds__(512, 4) void wo_gemm(
    const unsigned short* __restrict__ A, const unsigned short* __restrict__ Bw,
    int M, int N, int K, const float* __restrict__ resid, float* __restrict__ outF) {
  gemm128_body<2>(A, Bw, M, N, K, resid, outF, nullptr, nullptr, nullptr);
}
__global__ __launch_bounds__(512, 4) void ffn2_gemm(
    const unsigned short* __restrict__ A, const unsigned short* __restrict__ Bw,
    int M, int N, int K, const float* __restrict__ resid, float* __restrict__ outF) {
  gemm128_body<2>(A, Bw, M, N, K, resid, outF, nullptr, nullptr, nullptr);
}

// ---------------- Flash attention (causal, swapped-QK^T, in-lane softmax) ----
// __launch_bounds__(512, 1): min-waves 1 -> full VGPR budget, no spills
// (round-6 showed VGPR_Count 48 = spilled sc/oacc, ~5x serial-model slowdown).
__global__ __launch_bounds__(512, 1) void attn_kernel(
    const unsigned short* __restrict__ qg, const unsigned short* __restrict__ kg,
    const unsigned short* __restrict__ vt, unsigned short* __restrict__ og) {
  __shared__ __attribute__((aligned(16))) unsigned short Kl[64 * 64];
  __shared__ __attribute__((aligned(16))) unsigned short Vl[64 * 64];
  __shared__ __attribute__((aligned(16))) unsigned short Pl[8][16 * 64];
  const int t = threadIdx.x, lane = t & 63, w = t >> 6;
  const int lg = lane >> 4, ln = lane & 15;
  const int bh = blockIdx.y, b = bh >> 4, h = bh & 15;
  const int q0 = ((int)gridDim.x - 1 - (int)blockIdx.x) * 128;
  const int qw = q0 + w * 16;

  bf16x8 aq[2];
  {
    const unsigned short* qp =
        qg + (size_t)(b * S_ + qw + ln) * D_ + h * DK_ + lg * 8;
    aq[0] = *reinterpret_cast<const bf16x8*>(qp);
    aq[1] = *reinterpret_cast<const bf16x8*>(qp + 32);
  }
  float mr = -1e30f, lr = 0.f;
  f32x4 oacc[4] = {};
  const int dqt = qw >> 6;
  const int nt = (q0 >> 6) + 2;
  const float SCL = 0.125f * 1.44269504089f;

  for (int kt = 0; kt < nt; ++kt) {
    const int kv0 = kt * 64;
    {
      int row = t >> 3, cg = t & 7, sg = cg ^ (row & 7);
      gload_lds16(kg + (size_t)(b * S_ + kv0 + row) * D_ + h * DK_ + sg * 8, &Kl[t * 8]);
      gload_lds16(vt + (size_t)(b * D_ + h * DK_ + row) * S_ + kv0 + sg * 8, &Vl[t * 8]);
    }
    __syncthreads();
    if (kt <= dqt) {
      f32x4 sc[4] = {};
#pragma unroll
      for (int n = 0; n < 4; ++n) {
        int r = n * 16 + ln;
#pragma unroll
        for (int c = 0; c < 2; ++c) {
          int cg = (c * 4 + lg) ^ (r & 7);
          bf16x8 bk = *reinterpret_cast<const bf16x8*>(&Kl[r * 64 + cg * 8]);
          sc[n] = __builtin_amdgcn_mfma_f32_16x16x32_bf16(bk, aq[c], sc[n], 0, 0, 0);
        }
      }
      const bool diag = (kt == dqt);
      const int qi = qw + ln;
      float mx = -1e30f;
#pragma unroll
      for (int n = 0; n < 4; ++n)
#pragma unroll
        for (int j = 0; j < 4; ++j) {
          float s = sc[n][j] * SCL;
          if (diag && (kv0 + n * 16 + lg * 4 + j) > qi) s = -1e30f;
          sc[n][j] = s;
          mx = fmaxf(mx, s);
        }
      mx = fmaxf(mx, __shfl_xor(mx, 16));
      mx = fmaxf(mx, __shfl_xor(mx, 32));
      float mn = fmaxf(mr, mx);
      float sf = exp2f(mr - mn);
      mr = mn;
      float ps = 0.f;
#pragma unroll
      for (int n = 0; n < 4; ++n)
#pragma unroll
        for (int j = 0; j < 4; ++j) {
          float p = exp2f(sc[n][j] - mn);
          sc[n][j] = p;
          ps += p;
        }
      ps += __shfl_xor(ps, 16);
      ps += __shfl_xor(ps, 32);
      lr = lr * sf + ps;
#pragma unroll
      for (int j = 0; j < 4; ++j) {
        float sfj = __shfl(sf, lg * 4 + j);
#pragma unroll
        for (int f = 0; f < 4; ++f) oacc[f][j] *= sfj;
      }
      unsigned short* pl = Pl[w];
#pragma unroll
      for (int n = 0; n < 4; ++n) {
        int kvc = n * 16 + lg * 4;
        int cg = (kvc >> 3) ^ (ln & 7);
        unsigned short* dst = &pl[ln * 64 + cg * 8 + (kvc & 7)];
        unsigned p01 = (unsigned)bf16r(sc[n][0]) | ((unsigned)bf16r(sc[n][1]) << 16);
        unsigned p23 = (unsigned)bf16r(sc[n][2]) | ((unsigned)bf16r(sc[n][3]) << 16);
        *reinterpret_cast<unsigned*>(dst) = p01;
        *reinterpret_cast<unsigned*>(dst + 2) = p23;
      }
#pragma unroll
      for (int c = 0; c < 2; ++c) {
        int cgp = (c * 4 + lg) ^ (ln & 7);
        bf16x8 pa = *reinterpret_cast<const bf16x8*>(&pl[ln * 64 + cgp * 8]);
#pragma unroll
        for (int f = 0; f < 4; ++f) {
          int dv = f * 16 + ln;
          int cgv = (c * 4 + lg) ^ (dv & 7);
          bf16x8 vb = *reinterpret_cast<const bf16x8*>(&Vl[dv * 64 + cgv * 8]);
          oacc[f] = __builtin_amdgcn_mfma_f32_16x16x32_bf16(pa, vb, oacc[f], 0, 0, 0);
        }
      }
    }
    __syncthreads();
  }
#pragma unroll
  for (int j = 0; j < 4; ++j) {
    float lj = __shfl(lr, lg * 4 + j);
    float inv = 1.0f / lj;
    int row = b * S_ + qw + lg * 4 + j;
#pragma unroll
    for (int f = 0; f < 4; ++f)
      og[(size_t)row * D_ + h * DK_ + f * 16 + ln] = bf16r(oacc[f][j] * inv);
  }
}

// ---------------- launch ----------------
extern "C" void kernel_launch(void* const* d_in, const int* in_sizes, int n_in,
                              void* d_out, int out_size, void* d_ws, size_t ws_size,
                              hipStream_t stream) {
  const float* x  = (const float*)d_in[0];
  const float* wq = (const float*)d_in[1];
  const float* wk = (const float*)d_in[2];
  const float* wv = (const float*)d_in[3];
  const float* wo = (const float*)d_in[4];
  const float* w1 = (const float*)d_in[5];
  const float* w2 = (const float*)d_in[6];
  const float* g1 = (const float*)d_in[7];
  const float* g2 = (const float*)d_in[8];
  float* out = (float*)d_out;

  char* ws = (char*)d_ws;
  const size_t MB = 1024 * 1024;
  unsigned short* wqkv_b = (unsigned short*)(ws + 0 * MB);   // [3072][1024]
  unsigned short* wo_b   = (unsigned short*)(ws + 6 * MB);
  unsigned short* w1_b   = (unsigned short*)(ws + 8 * MB);
  unsigned short* w2_b   = (unsigned short*)(ws + 16 * MB);
  unsigned short* h_b    = (unsigned short*)(ws + 24 * MB);
  unsigned short* q_b    = (unsigned short*)(ws + 32 * MB);
  unsigned short* k_b    = (unsigned short*)(ws + 40 * MB);
  unsigned short* vt_b   = (unsigned short*)(ws + 48 * MB);
  unsigned short* o_b    = (unsigned short*)(ws + 56 * MB);
  float*          x1     = (float*)(ws + 64 * MB);
  unsigned short* mid    = (unsigned short*)(ws + 80 * MB);

  CvtArgs ca;
  ca.src[0] = wq; ca.dst[0] = wqkv_b;
  ca.src[1] = wk; ca.dst[1] = wqkv_b + (size_t)D_ * D_;
  ca.src[2] = wv; ca.dst[2] = wqkv_b + (size_t)2 * D_ * D_;
  ca.src[3] = wo; ca.dst[3] = wo_b;
  ca.src[4] = w1; ca.dst[4] = w1_b;
  ca.src[5] = w2; ca.dst[5] = w2_b;
  int q4 = D_ * D_ / 4, f4 = F_ * D_ / 4;
  ca.start[0] = 0;
  ca.start[1] = q4;
  ca.start[2] = 2 * q4;
  ca.start[3] = 3 * q4;
  ca.start[4] = 4 * q4;
  ca.start[5] = 4 * q4 + f4;
  ca.start[6] = 4 * q4 + 2 * f4;
  cvt_all_kernel<<<(ca.start[6] + 255) / 256, 256, 0, stream>>>(ca);

  rmsnorm_kernel<<<NTOK, 256, 0, stream>>>(x, g1, h_b);

  // fused QKV: N=3072, grid 24x32
  qkv_gemm<<<dim3(3 * D_ / 128, NTOK / 128), dim3(512), 0, stream>>>(
      h_b, wqkv_b, NTOK, 3 * D_, D_, q_b, k_b, vt_b);

  attn_kernel<<<dim3(S_ / 128, B_ * H_), dim3(512), 0, stream>>>(q_b, k_b, vt_b, o_b);

  // WO + residual: N=1024, grid 8x32
  wo_gemm<<<dim3(D_ / 128, NTOK / 128), dim3(512), 0, stream>>>(
      o_b, wo_b, NTOK, D_, D_, x, x1);

  rmsnorm_kernel<<<NTOK, 256, 0, stream>>>(x1, g2, h_b);

  // FFN1 + fast GELU: N=4096, grid 32x32
  ffn1_gemm<<<dim3(F_ / 128, NTOK / 128), dim3(512), 0, stream>>>(
      h_b, w1_b, NTOK, F_, D_, mid);

  // FFN2 + residual: N=1024, grid 8x32
  ffn2_gemm<<<dim3(D_ / 128, NTOK / 128), dim3(512), 0, stream>>>(
      mid, w2_b, NTOK, D_, F_, x1, out);
}

// Round 8
// 251.307 us; speedup vs baseline: 1.5824x; 1.1139x over previous
//
#include <hip/hip_runtime.h>
#include <hip/hip_bf16.h>
#include <math.h>

#define B_   2
#define S_   2048
#define D_   1024
#define H_   16
#define DK_  64
#define F_   4096
#define NTOK (B_ * S_)

typedef __bf16 bf16x8 __attribute__((ext_vector_type(8)));
typedef float  f32x4  __attribute__((ext_vector_type(4)));

__device__ __forceinline__ unsigned short bf16r(float f) {
  unsigned u = __builtin_bit_cast(unsigned, f);
  u += 0x7fffu + ((u >> 16) & 1u);
  return (unsigned short)(u >> 16);
}

__device__ __forceinline__ void gload_lds16(const void* g, void* l) {
  __builtin_amdgcn_global_load_lds(
      (__attribute__((address_space(1))) void*)g,
      (__attribute__((address_space(3))) void*)l, 16, 0, 0);
}

// 32-bit LDS byte offset of an LDS pointer (for inline-asm DS ops)
__device__ __forceinline__ unsigned lds_off(void* p) {
  return (unsigned)(size_t)(__attribute__((address_space(3))) void*)p;
}
// opaque ds_read_b128: compiler can't see LDS aliasing -> no auto vmcnt(0) drain
__device__ __forceinline__ bf16x8 ds_read16(unsigned a) {
  bf16x8 r;
  asm volatile("ds_read_b128 %0, %1" : "=v"(r) : "v"(a));
  return r;
}
__device__ __forceinline__ void ds_write32(unsigned a, unsigned v) {
  asm volatile("ds_write_b32 %0, %1" : : "v"(a), "v"(v));
}
// raw v_exp_f32 (2^x); libm exp2f is a multi-instruction call
__device__ __forceinline__ float fexp2(float x) {
  float r;
  asm volatile("v_exp_f32 %0, %1\n\ts_nop 0" : "=v"(r) : "v"(x));
  return r;
}

// tanh-form GELU via v_exp (max abs err ~3e-3; validated rounds 5-7)
__device__ __forceinline__ float gelu_fast(float x) {
  float y = 0.7978845608f * x * (1.0f + 0.044715f * x * x);
  float e = fexp2(2.885390082f * y);  // e^(2y)
  float t = 1.0f - 2.0f / (e + 1.0f);
  return 0.5f * x * (1.0f + t);
}

// ---------------- all weights fp32 -> bf16, one launch ----------------
struct CvtArgs {
  const float* src[6];
  unsigned short* dst[6];
  int start[7];
};
__global__ __launch_bounds__(256) void cvt_all_kernel(CvtArgs a) {
  int i = blockIdx.x * blockDim.x + threadIdx.x;
  if (i >= a.start[6]) return;
  int k = 0;
#pragma unroll
  for (int j = 1; j < 6; ++j)
    if (i >= a.start[j]) k = j;
  int off = i - a.start[k];
  float4 v = reinterpret_cast<const float4*>(a.src[k])[off];
  ushort4 o;
  o.x = bf16r(v.x); o.y = bf16r(v.y); o.z = bf16r(v.z); o.w = bf16r(v.w);
  reinterpret_cast<ushort4*>(a.dst[k])[off] = o;
}

// ---------------- RMSNorm (fp32 in, bf16 out) ----------------
__global__ __launch_bounds__(256) void rmsnorm_kernel(
    const float* __restrict__ x, const float* __restrict__ g,
    unsigned short* __restrict__ out) {
  int row = blockIdx.x;
  int t = threadIdx.x, lane = t & 63, w = t >> 6;
  float4 v = reinterpret_cast<const float4*>(x + (size_t)row * D_)[t];
  float ss = v.x * v.x + v.y * v.y + v.z * v.z + v.w * v.w;
#pragma unroll
  for (int d = 1; d < 64; d <<= 1) ss += __shfl_xor(ss, d);
  __shared__ float red[4];
  if (lane == 0) red[w] = ss;
  __syncthreads();
  float tot = red[0] + red[1] + red[2] + red[3];
  float rstd = rsqrtf(tot * (1.0f / D_) + 1e-5f);
  float4 gv = reinterpret_cast<const float4*>(g)[t];
  ushort4 o;
  o.x = bf16r(v.x * rstd * gv.x);
  o.y = bf16r(v.y * rstd * gv.y);
  o.z = bf16r(v.z * rstd * gv.z);
  o.w = bf16r(v.w * rstd * gv.w);
  reinterpret_cast<ushort4*>(out + (size_t)row * D_)[t] = o;
}

// ======== 128x128 4-deep pipelined GEMM, asm-DS reads, 1 barrier/tile =======
// EPI 1: GELU->bf16 | 2: +resid->fp32 | 4: QKV scatter (q, k, v^T)
template <int EPI>
__device__ __forceinline__ void gemm128_body(
    const unsigned short* __restrict__ A, const unsigned short* __restrict__ Bw,
    int M, int N, int K,
    const float* __restrict__ resid, float* __restrict__ outF,
    unsigned short* __restrict__ outB, unsigned short* __restrict__ outB2,
    unsigned short* __restrict__ outB3) {
  constexpr int BUFU = 256 * 32;  // ushorts per buffer (A 4096 + B 4096)
  __shared__ __attribute__((aligned(16))) unsigned short lds[4 * BUFU];
  const int t = threadIdx.x, lane = t & 63, w = t >> 6;
  const int wm = w >> 2, wn = w & 3;
  const int lg = lane >> 4, ln = lane & 15;

  // bijective XCD-aware rect remap (all grids: gx%4==0, gy%2==0)
  const int gx = gridDim.x;
  int bid = blockIdx.y * gx + blockIdx.x;
  int RX = gx >> 2, RY = gridDim.y >> 1;
  int xcd = bid & 7, c = bid >> 3;
  int bx = (xcd & 3) * RX + (c % RX);
  int by = (xcd >> 2) * RY + (c / RX);
  const int m0 = by * 128, n0 = bx * 128;

  const int nt = K >> 5;

  auto stage = [&](int tile) {
    const int buf = tile & 3;
    const int k0 = tile << 5;
    unsigned short* la = &lds[buf * BUFU];
    unsigned short* lb = la + 4096;
    int Ln = t >> 3, p = t & 7, u = p ^ (Ln & 7);
    int row = 2 * Ln + (u >> 2), cg = u & 3;
    gload_lds16(A + (size_t)(m0 + row) * K + k0 + cg * 8, &la[t * 8]);
    gload_lds16(Bw + (size_t)(n0 + row) * K + k0 + cg * 8, &lb[t * 8]);
  };

  stage(0);
  if (nt > 1) stage(1);
  if (nt > 2) stage(2);

  const unsigned base0 = lds_off(lds);
  unsigned offA[4], offB[2];  // byte offsets within a buffer
#pragma unroll
  for (int m = 0; m < 4; ++m) {
    int r = wm * 64 + m * 16 + ln;
    int Ln = r >> 1, p = ((r & 1) * 4 + lg) ^ (Ln & 7);
    offA[m] = (unsigned)((Ln * 64 + p * 8) * 2);
  }
#pragma unroll
  for (int n = 0; n < 2; ++n) {
    int r = wn * 32 + n * 16 + ln;
    int Ln = r >> 1, p = ((r & 1) * 4 + lg) ^ (Ln & 7);
    offB[n] = (unsigned)(8192 + (Ln * 64 + p * 8) * 2);
  }

  f32x4 acc[4][2] = {};

  for (int tile = 0; tile < nt; ++tile) {
    const int rem = nt - 1 - tile;
    if (rem >= 2)      { asm volatile("s_waitcnt vmcnt(4)"); }
    else if (rem == 1) { asm volatile("s_waitcnt vmcnt(2)"); }
    else               { asm volatile("s_waitcnt vmcnt(0)"); }
    __builtin_amdgcn_sched_barrier(0);
    __builtin_amdgcn_s_barrier();
    const unsigned bb = base0 + (unsigned)((tile & 3) * (BUFU * 2));
    bf16x8 af[4], bf[2];
#pragma unroll
    for (int m = 0; m < 4; ++m) af[m] = ds_read16(bb + offA[m]);
#pragma unroll
    for (int n = 0; n < 2; ++n) bf[n] = ds_read16(bb + offB[n]);
    if (tile + 3 < nt) stage(tile + 3);
    asm volatile("s_waitcnt lgkmcnt(0)");
    __builtin_amdgcn_sched_barrier(0);
    __builtin_amdgcn_s_setprio(1);
#pragma unroll
    for (int m = 0; m < 4; ++m)
#pragma unroll
      for (int n = 0; n < 2; ++n)
        acc[m][n] = __builtin_amdgcn_mfma_f32_16x16x32_bf16(af[m], bf[n], acc[m][n], 0, 0, 0);
    __builtin_amdgcn_s_setprio(0);
  }

  const int rbase = m0 + wm * 64 + lg * 4;
  const int cbase = n0 + wn * 32 + ln;
#pragma unroll
  for (int m = 0; m < 4; ++m) {
#pragma unroll
    for (int n = 0; n < 2; ++n) {
      int col = cbase + n * 16;
#pragma unroll
      for (int j = 0; j < 4; ++j) {
        int row = rbase + m * 16 + j;
        float v = acc[m][n][j];
        if (EPI == 1) {
          outB[(size_t)row * N + col] = bf16r(gelu_fast(v));
        } else if (EPI == 2) {
          outF[(size_t)row * N + col] = v + resid[(size_t)row * N + col];
        } else {  // EPI 4: QKV scatter (q, k row-major; v transposed)
          if (col < D_) {
            outB[(size_t)row * D_ + col] = bf16r(v);
          } else if (col < 2 * D_) {
            outB2[(size_t)row * D_ + (col - D_)] = bf16r(v);
          } else {
            int bb2 = row >> 11, s = row & (S_ - 1);
            outB3[((size_t)(bb2 * D_) + (col - 2 * D_)) * S_ + s] = bf16r(v);
          }
        }
      }
    }
  }
}

__global__ __launch_bounds__(512, 4) void qkv_gemm(
    const unsigned short* __restrict__ A, const unsigned short* __restrict__ Bw,
    int M, int N, int K, unsigned short* o1, unsigned short* o2, unsigned short* o3) {
  gemm128_body<4>(A, Bw, M, N, K, nullptr, nullptr, o1, o2, o3);
}
__global__ __launch_bounds__(512, 4) void ffn1_gemm(
    const unsigned short* __restrict__ A, const unsigned short* __restrict__ Bw,
    int M, int N, int K, unsigned short* o1) {
  gemm128_body<1>(A, Bw, M, N, K, nullptr, nullptr, o1, nullptr, nullptr);
}
__global__ __launch_bounds__(512, 4) void wo_gemm(
    const unsigned short* __restrict__ A, const unsigned short* __restrict__ Bw,
    int M, int N, int K, const float* __restrict__ resid, float* __restrict__ outF) {
  gemm128_body<2>(A, Bw, M, N, K, resid, outF, nullptr, nullptr, nullptr);
}
__global__ __launch_bounds__(512, 4) void ffn2_gemm(
    const unsigned short* __restrict__ A, const unsigned short* __restrict__ Bw,
    int M, int N, int K, const float* __restrict__ resid, float* __restrict__ outF) {
  gemm128_body<2>(A, Bw, M, N, K, resid, outF, nullptr, nullptr, nullptr);
}

// ---------------- Flash attention: 2-deep K/V double-buffer, asm DS ops ------
// grid 512 x 1D; chunked XCD remap; 8 waves x 16 q-rows (QBLK=128).
__global__ __launch_bounds__(512, 1) void attn_kernel(
    const unsigned short* __restrict__ qg, const unsigned short* __restrict__ kg,
    const unsigned short* __restrict__ vt, unsigned short* __restrict__ og) {
  __shared__ __attribute__((aligned(16))) unsigned short Kl[2][4096];
  __shared__ __attribute__((aligned(16))) unsigned short Vl[2][4096];
  __shared__ __attribute__((aligned(16))) unsigned short Pl[8][1024];
  const int t = threadIdx.x, lane = t & 63, w = t >> 6;
  const int lg = lane >> 4, ln = lane & 15;

  // chunked XCD remap: consecutive dispatch ids fill one XCD with one bh group
  int bid = blockIdx.x;
  int nl = (bid & 7) * 64 + (bid >> 3);
  int bh = nl >> 4, qxr = nl & 15;
  int b = bh >> 4, h = bh & 15;
  int q0 = (15 - qxr) * 128;  // heavy blocks first within each XCD chunk
  int qw = q0 + w * 16;

  bf16x8 aq[2];
  {
    const unsigned short* qp =
        qg + (size_t)(b * S_ + qw + ln) * D_ + h * DK_ + lg * 8;
    aq[0] = *reinterpret_cast<const bf16x8*>(qp);
    aq[1] = *reinterpret_cast<const bf16x8*>(qp + 32);
  }
  // force the q-load wait OUTSIDE the loop (else compiler re-waits every iter)
  asm volatile("" : : "v"(aq[0]), "v"(aq[1]));

  float mr = -1e30f, lr = 0.f;  // stats for q = qw + ln (replicated over lg)
  f32x4 oacc[4] = {};
  const int dqt = qw >> 6;
  const int nt = (q0 >> 6) + 2;
  const float SCL = 0.125f * 1.44269504089f;  // 1/sqrt(dk) * log2(e)

  auto stage = [&](int kt) {
    const int buf = kt & 1;
    const int kv0 = kt * 64;
    int row = t >> 3, cg = t & 7, sg = cg ^ (row & 7);  // pre-swizzled source
    gload_lds16(kg + (size_t)(b * S_ + kv0 + row) * D_ + h * DK_ + sg * 8, &Kl[buf][t * 8]);
    gload_lds16(vt + (size_t)(b * D_ + h * DK_ + row) * S_ + kv0 + sg * 8, &Vl[buf][t * 8]);
  };
  stage(0);

  const unsigned kbase = lds_off(&Kl[0][0]);
  const unsigned vbase = lds_off(&Vl[0][0]);
  const unsigned pbase = lds_off(&Pl[w][0]);

  for (int kt = 0; kt < nt; ++kt) {
    asm volatile("s_waitcnt vmcnt(0)");  // stage(kt) landed (issued 1 iter ago)
    __builtin_amdgcn_sched_barrier(0);
    __builtin_amdgcn_s_barrier();
    const unsigned kb = kbase + (unsigned)((kt & 1) * 8192);
    const unsigned vb = vbase + (unsigned)((kt & 1) * 8192);
    const int kv0 = kt * 64;
    if (kt <= dqt) {
      // ---- QK^T (swapped: lane holds P[kv rows][q=ln]) ----
      f32x4 sc[4] = {};
      bf16x8 kf[4];
#pragma unroll
      for (int n = 0; n < 4; ++n) {
        int r = n * 16 + ln;
        int cg0 = lg ^ (r & 7);
        kf[n] = ds_read16(kb + (unsigned)((r * 64 + cg0 * 8) * 2));
      }
      if (kt + 1 < nt) stage(kt + 1);  // issue next K/V DMA under compute
      asm volatile("s_waitcnt lgkmcnt(0)");
      __builtin_amdgcn_sched_barrier(0);
#pragma unroll
      for (int n = 0; n < 4; ++n)
        sc[n] = __builtin_amdgcn_mfma_f32_16x16x32_bf16(kf[n], aq[0], sc[n], 0, 0, 0);
#pragma unroll
      for (int n = 0; n < 4; ++n) {
        int r = n * 16 + ln;
        int cg1 = (4 + lg) ^ (r & 7);
        kf[n] = ds_read16(kb + (unsigned)((r * 64 + cg1 * 8) * 2));
      }
      asm volatile("s_waitcnt lgkmcnt(0)");
      __builtin_amdgcn_sched_barrier(0);
#pragma unroll
      for (int n = 0; n < 4; ++n)
        sc[n] = __builtin_amdgcn_mfma_f32_16x16x32_bf16(kf[n], aq[1], sc[n], 0, 0, 0);
      // ---- softmax (in-lane over 16 kv each, 2 shfl for cross-group) ----
      const bool diag = (kt == dqt);
      const int qi = qw + ln;
      float mx = -1e30f;
#pragma unroll
      for (int n = 0; n < 4; ++n)
#pragma unroll
        for (int j = 0; j < 4; ++j) {
          float s = sc[n][j] * SCL;
          if (diag && (kv0 + n * 16 + lg * 4 + j) > qi) s = -1e30f;
          sc[n][j] = s;
          mx = fmaxf(mx, s);
        }
      mx = fmaxf(mx, __shfl_xor(mx, 16));
      mx = fmaxf(mx, __shfl_xor(mx, 32));
      float mn = fmaxf(mr, mx);
      float ps = 0.f;
#pragma unroll
      for (int n = 0; n < 4; ++n)
#pragma unroll
        for (int j = 0; j < 4; ++j) {
          float p = fexp2(sc[n][j] - mn);
          sc[n][j] = p;
          ps += p;
        }
      ps += __shfl_xor(ps, 16);
      ps += __shfl_xor(ps, 32);
      if (__all(mx <= mr)) {  // sf == 1 exactly: skip rescale (no numerics change)
        lr += ps;
      } else {
        float sf = fexp2(mr - mn);
        mr = mn;
        lr = lr * sf + ps;
#pragma unroll
        for (int j = 0; j < 4; ++j) {
          float sfj = __shfl(sf, lg * 4 + j);
#pragma unroll
          for (int f = 0; f < 4; ++f) oacc[f][j] *= sfj;
        }
      }
      // ---- P -> bf16 LDS (asm b32 writes, swizzled) ----
#pragma unroll
      for (int n = 0; n < 4; ++n) {
        int kvc = n * 16 + lg * 4;
        int cg = (kvc >> 3) ^ (ln & 7);
        unsigned pa_addr = pbase + (unsigned)((ln * 64 + cg * 8 + (kvc & 7)) * 2);
        unsigned p01 = (unsigned)bf16r(sc[n][0]) | ((unsigned)bf16r(sc[n][1]) << 16);
        unsigned p23 = (unsigned)bf16r(sc[n][2]) | ((unsigned)bf16r(sc[n][3]) << 16);
        ds_write32(pa_addr, p01);
        ds_write32(pa_addr + 4, p23);
      }
      asm volatile("s_waitcnt lgkmcnt(0)");
      __builtin_amdgcn_sched_barrier(0);
      // ---- PV: A = P rows (q), B = V^T rows (d) ----
#pragma unroll
      for (int c = 0; c < 2; ++c) {
        unsigned cgp = (unsigned)((c * 4 + lg) ^ (ln & 7));
        bf16x8 pa = ds_read16(pbase + (unsigned)(ln * 128) + cgp * 16);
        bf16x8 vf[4];
#pragma unroll
        for (int f = 0; f < 4; ++f) {
          int dv = f * 16 + ln;
          int cgv = (c * 4 + lg) ^ (dv & 7);
          vf[f] = ds_read16(vb + (unsigned)((dv * 64 + cgv * 8) * 2));
        }
        asm volatile("s_waitcnt lgkmcnt(0)");
        __builtin_amdgcn_sched_barrier(0);
#pragma unroll
        for (int f = 0; f < 4; ++f)
          oacc[f] = __builtin_amdgcn_mfma_f32_16x16x32_bf16(pa, vf[f], oacc[f], 0, 0, 0);
      }
    }
    // note: kt > dqt only happens at kt == nt-1 (waves 0-3), where no stage
    // call is needed (kt+1 == nt) -- staging stays block-uniform.
  }
#pragma unroll
  for (int j = 0; j < 4; ++j) {
    float lj = __shfl(lr, lg * 4 + j);
    float inv = 1.0f / lj;
    int row = b * S_ + qw + lg * 4 + j;
#pragma unroll
    for (int f = 0; f < 4; ++f)
      og[(size_t)row * D_ + h * DK_ + f * 16 + ln] = bf16r(oacc[f][j] * inv);
  }
}

// ---------------- launch ----------------
extern "C" void kernel_launch(void* const* d_in, const int* in_sizes, int n_in,
                              void* d_out, int out_size, void* d_ws, size_t ws_size,
                              hipStream_t stream) {
  const float* x  = (const float*)d_in[0];
  const float* wq = (const float*)d_in[1];
  const float* wk = (const float*)d_in[2];
  const float* wv = (const float*)d_in[3];
  const float* wo = (const float*)d_in[4];
  const float* w1 = (const float*)d_in[5];
  const float* w2 = (const float*)d_in[6];
  const float* g1 = (const float*)d_in[7];
  const float* g2 = (const float*)d_in[8];
  float* out = (float*)d_out;

  char* ws = (char*)d_ws;
  const size_t MB = 1024 * 1024;
  unsigned short* wqkv_b = (unsigned short*)(ws + 0 * MB);   // [3072][1024]
  unsigned short* wo_b   = (unsigned short*)(ws + 6 * MB);
  unsigned short* w1_b   = (unsigned short*)(ws + 8 * MB);
  unsigned short* w2_b   = (unsigned short*)(ws + 16 * MB);
  unsigned short* h_b    = (unsigned short*)(ws + 24 * MB);
  unsigned short* q_b    = (unsigned short*)(ws + 32 * MB);
  unsigned short* k_b    = (unsigned short*)(ws + 40 * MB);
  unsigned short* vt_b   = (unsigned short*)(ws + 48 * MB);
  unsigned short* o_b    = (unsigned short*)(ws + 56 * MB);
  float*          x1     = (float*)(ws + 64 * MB);
  unsigned short* mid    = (unsigned short*)(ws + 80 * MB);

  CvtArgs ca;
  ca.src[0] = wq; ca.dst[0] = wqkv_b;
  ca.src[1] = wk; ca.dst[1] = wqkv_b + (size_t)D_ * D_;
  ca.src[2] = wv; ca.dst[2] = wqkv_b + (size_t)2 * D_ * D_;
  ca.src[3] = wo; ca.dst[3] = wo_b;
  ca.src[4] = w1; ca.dst[4] = w1_b;
  ca.src[5] = w2; ca.dst[5] = w2_b;
  int q4 = D_ * D_ / 4, f4 = F_ * D_ / 4;
  ca.start[0] = 0;
  ca.start[1] = q4;
  ca.start[2] = 2 * q4;
  ca.start[3] = 3 * q4;
  ca.start[4] = 4 * q4;
  ca.start[5] = 4 * q4 + f4;
  ca.start[6] = 4 * q4 + 2 * f4;
  cvt_all_kernel<<<(ca.start[6] + 255) / 256, 256, 0, stream>>>(ca);

  rmsnorm_kernel<<<NTOK, 256, 0, stream>>>(x, g1, h_b);

  // fused QKV: N=3072, grid 24x32
  qkv_gemm<<<dim3(3 * D_ / 128, NTOK / 128), dim3(512), 0, stream>>>(
      h_b, wqkv_b, NTOK, 3 * D_, D_, q_b, k_b, vt_b);

  attn_kernel<<<dim3(512), dim3(512), 0, stream>>>(q_b, k_b, vt_b, o_b);

  // WO + residual: N=1024, grid 8x32
  wo_gemm<<<dim3(D_ / 128, NTOK / 128), dim3(512), 0, stream>>>(
      o_b, wo_b, NTOK, D_, D_, x, x1);

  rmsnorm_kernel<<<NTOK, 256, 0, stream>>>(x1, g2, h_b);

  // FFN1 + fast GELU: N=4096, grid 32x32
  ffn1_gemm<<<dim3(F_ / 128, NTOK / 128), dim3(512), 0, stream>>>(
      h_b, w1_b, NTOK, F_, D_, mid);

  // FFN2 + residual: N=1024, grid 8x32
  ffn2_gemm<<<dim3(D_ / 128, NTOK / 128), dim3(512), 0, stream>>>(
      mid, w2_b, NTOK, D_, F_, x1, out);
}

// Round 9
// 248.785 us; speedup vs baseline: 1.5985x; 1.0101x over previous
//
#include <hip/hip_runtime.h>
#include <hip/hip_bf16.h>
#include <math.h>

#define B_   2
#define S_   2048
#define D_   1024
#define H_   16
#define DK_  64
#define F_   4096
#define NTOK (B_ * S_)

typedef __bf16 bf16x8 __attribute__((ext_vector_type(8)));
typedef float  f32x4  __attribute__((ext_vector_type(4)));

__device__ __forceinline__ unsigned short bf16r(float f) {
  unsigned u = __builtin_bit_cast(unsigned, f);
  u += 0x7fffu + ((u >> 16) & 1u);
  return (unsigned short)(u >> 16);
}

__device__ __forceinline__ void gload_lds16(const void* g, void* l) {
  __builtin_amdgcn_global_load_lds(
      (__attribute__((address_space(1))) void*)g,
      (__attribute__((address_space(3))) void*)l, 16, 0, 0);
}

__device__ __forceinline__ unsigned lds_off(void* p) {
  return (unsigned)(size_t)(__attribute__((address_space(3))) void*)p;
}
__device__ __forceinline__ bf16x8 ds_read16(unsigned a) {
  bf16x8 r;
  asm volatile("ds_read_b128 %0, %1" : "=v"(r) : "v"(a));
  return r;
}
__device__ __forceinline__ void ds_write32(unsigned a, unsigned v) {
  asm volatile("ds_write_b32 %0, %1" : : "v"(a), "v"(v));
}
__device__ __forceinline__ float fexp2(float x) {
  float r;
  asm volatile("v_exp_f32 %0, %1\n\ts_nop 0" : "=v"(r) : "v"(x));
  return r;
}
__device__ __forceinline__ unsigned cvt_pk_bf16(float lo, float hi) {
  unsigned r;
  asm volatile("v_cvt_pk_bf16_f32 %0, %1, %2" : "=v"(r) : "v"(lo), "v"(hi));
  return r;
}

// tanh-form GELU via v_exp (max abs err ~3e-3; validated rounds 5-8)
__device__ __forceinline__ float gelu_fast(float x) {
  float y = 0.7978845608f * x * (1.0f + 0.044715f * x * x);
  float e = fexp2(2.885390082f * y);
  float t = 1.0f - 2.0f / (e + 1.0f);
  return 0.5f * x * (1.0f + t);
}

#define QSCL 0.18033688f  /* (1/8) * log2(e), folded into Q at QKV epilogue */

// ---------------- all weights fp32 -> bf16, one launch ----------------
struct CvtArgs {
  const float* src[6];
  unsigned short* dst[6];
  int start[7];
};
__global__ __launch_bounds__(256) void cvt_all_kernel(CvtArgs a) {
  int i = blockIdx.x * blockDim.x + threadIdx.x;
  if (i >= a.start[6]) return;
  int k = 0;
#pragma unroll
  for (int j = 1; j < 6; ++j)
    if (i >= a.start[j]) k = j;
  int off = i - a.start[k];
  float4 v = reinterpret_cast<const float4*>(a.src[k])[off];
  ushort4 o;
  o.x = bf16r(v.x); o.y = bf16r(v.y); o.z = bf16r(v.z); o.w = bf16r(v.w);
  reinterpret_cast<ushort4*>(a.dst[k])[off] = o;
}

// ---------------- RMSNorm (fp32 in, bf16 out) ----------------
__global__ __launch_bounds__(256) void rmsnorm_kernel(
    const float* __restrict__ x, const float* __restrict__ g,
    unsigned short* __restrict__ out) {
  int row = blockIdx.x;
  int t = threadIdx.x, lane = t & 63, w = t >> 6;
  float4 v = reinterpret_cast<const float4*>(x + (size_t)row * D_)[t];
  float ss = v.x * v.x + v.y * v.y + v.z * v.z + v.w * v.w;
#pragma unroll
  for (int d = 1; d < 64; d <<= 1) ss += __shfl_xor(ss, d);
  __shared__ float red[4];
  if (lane == 0) red[w] = ss;
  __syncthreads();
  float tot = red[0] + red[1] + red[2] + red[3];
  float rstd = rsqrtf(tot * (1.0f / D_) + 1e-5f);
  float4 gv = reinterpret_cast<const float4*>(g)[t];
  ushort4 o;
  o.x = bf16r(v.x * rstd * gv.x);
  o.y = bf16r(v.y * rstd * gv.y);
  o.z = bf16r(v.z * rstd * gv.z);
  o.w = bf16r(v.w * rstd * gv.w);
  reinterpret_cast<ushort4*>(out + (size_t)row * D_)[t] = o;
}

// ======== 256x128 pipelined GEMM (8 waves x 64x64, NBUF=3, BK=32) ===========
// Per tile: 8 ds_read + 16 MFMA per wave (2 phases of 8), one barrier, counted
// bare vmcnt(3). EPI 1: GELU->bf16 | 4: QKV scatter (q scaled, k, v^T)
template <int EPI>
__device__ __forceinline__ void gemm256_body(
    const unsigned short* __restrict__ A, const unsigned short* __restrict__ Bw,
    int M, int N, int K,
    unsigned short* __restrict__ outB, unsigned short* __restrict__ outB2,
    unsigned short* __restrict__ outB3) {
  constexpr int BUFU = 12288;  // ushorts: A 8192 (256x32) + B 4096 (128x32)
  __shared__ __attribute__((aligned(16))) unsigned short lds[3 * BUFU];  // 72 KB
  const int t = threadIdx.x, lane = t & 63, w = t >> 6;
  const int wm = w >> 1, wn = w & 1;
  const int lg = lane >> 4, ln = lane & 15;

  const int gx = gridDim.x;
  int bid = blockIdx.y * gx + blockIdx.x;
  int xcd = bid & 7, c = bid >> 3;
  int RX = gx >> 2, RY = gridDim.y >> 1;
  int bx = (xcd & 3) * RX + (c % RX);
  int by = (xcd >> 2) * RY + (c / RX);
  const int m0 = by * 256, n0 = bx * 128;

  const int nt = K >> 5;

  auto stage = [&](int tile) {
    int buf = tile % 3;
    const int k0 = tile << 5;
    unsigned short* la = &lds[buf * BUFU];
    unsigned short* lb = la + 8192;
#pragma unroll
    for (int i = 0; i < 2; ++i) {
      int g = i * 512 + t;
      int Ln = g >> 3, p = g & 7, u = p ^ (Ln & 7);
      int row = 2 * Ln + (u >> 2), cg = u & 3;
      gload_lds16(A + (size_t)(m0 + row) * K + k0 + cg * 8, &la[g * 8]);
    }
    {
      int Ln = t >> 3, p = t & 7, u = p ^ (Ln & 7);
      int row = 2 * Ln + (u >> 2), cg = u & 3;
      gload_lds16(Bw + (size_t)(n0 + row) * K + k0 + cg * 8, &lb[t * 8]);
    }
  };

  stage(0);
  stage(1);

  const unsigned base0 = lds_off(lds);
  unsigned offA[4], offB[4];
#pragma unroll
  for (int m = 0; m < 4; ++m) {
    int r = wm * 64 + m * 16 + ln;
    int Ln = r >> 1, p = ((r & 1) * 4 + lg) ^ (Ln & 7);
    offA[m] = (unsigned)((Ln * 64 + p * 8) * 2);
  }
#pragma unroll
  for (int n = 0; n < 4; ++n) {
    int r = wn * 64 + n * 16 + ln;
    int Ln = r >> 1, p = ((r & 1) * 4 + lg) ^ (Ln & 7);
    offB[n] = (unsigned)(16384 + (Ln * 64 + p * 8) * 2);
  }

  f32x4 acc[4][4] = {};

  for (int tile = 0; tile < nt; ++tile) {
    if (tile + 1 < nt) { asm volatile("s_waitcnt vmcnt(3)"); }
    else               { asm volatile("s_waitcnt vmcnt(0)"); }
    __builtin_amdgcn_sched_barrier(0);
    __builtin_amdgcn_s_barrier();
    const unsigned bb = base0 + (unsigned)((tile % 3) * (BUFU * 2));
    bf16x8 af[4], bf0, bf1;
#pragma unroll
    for (int m = 0; m < 4; ++m) af[m] = ds_read16(bb + offA[m]);
    bf0 = ds_read16(bb + offB[0]);
    bf1 = ds_read16(bb + offB[1]);
    if (tile + 2 < nt) stage(tile + 2);
    asm volatile("s_waitcnt lgkmcnt(0)");
    __builtin_amdgcn_sched_barrier(0);
    __builtin_amdgcn_s_setprio(1);
#pragma unroll
    for (int m = 0; m < 4; ++m) {
      acc[m][0] = __builtin_amdgcn_mfma_f32_16x16x32_bf16(af[m], bf0, acc[m][0], 0, 0, 0);
      acc[m][1] = __builtin_amdgcn_mfma_f32_16x16x32_bf16(af[m], bf1, acc[m][1], 0, 0, 0);
    }
    __builtin_amdgcn_s_setprio(0);
    bf0 = ds_read16(bb + offB[2]);
    bf1 = ds_read16(bb + offB[3]);
    asm volatile("s_waitcnt lgkmcnt(0)");
    __builtin_amdgcn_sched_barrier(0);
    __builtin_amdgcn_s_setprio(1);
#pragma unroll
    for (int m = 0; m < 4; ++m) {
      acc[m][2] = __builtin_amdgcn_mfma_f32_16x16x32_bf16(af[m], bf0, acc[m][2], 0, 0, 0);
      acc[m][3] = __builtin_amdgcn_mfma_f32_16x16x32_bf16(af[m], bf1, acc[m][3], 0, 0, 0);
    }
    __builtin_amdgcn_s_setprio(0);
  }

  const int rbase = m0 + wm * 64 + lg * 4;
  const int cbase = n0 + wn * 64 + ln;
#pragma unroll
  for (int m = 0; m < 4; ++m) {
#pragma unroll
    for (int n = 0; n < 4; ++n) {
      int col = cbase + n * 16;
#pragma unroll
      for (int j = 0; j < 4; ++j) {
        int row = rbase + m * 16 + j;
        float v = acc[m][n][j];
        if (EPI == 1) {
          outB[(size_t)row * N + col] = bf16r(gelu_fast(v));
        } else {  // EPI 4: QKV scatter (q pre-scaled, k row-major, v^T)
          if (col < D_) {
            outB[(size_t)row * D_ + col] = bf16r(v * QSCL);
          } else if (col < 2 * D_) {
            outB2[(size_t)row * D_ + (col - D_)] = bf16r(v);
          } else {
            int bb2 = row >> 11, s = row & (S_ - 1);
            outB3[((size_t)(bb2 * D_) + (col - 2 * D_)) * S_ + s] = bf16r(v);
          }
        }
      }
    }
  }
}

__global__ __launch_bounds__(512, 4) void qkv_gemm(
    const unsigned short* __restrict__ A, const unsigned short* __restrict__ Bw,
    int M, int N, int K, unsigned short* o1, unsigned short* o2, unsigned short* o3) {
  gemm256_body<4>(A, Bw, M, N, K, o1, o2, o3);
}
__global__ __launch_bounds__(512, 4) void ffn1_gemm(
    const unsigned short* __restrict__ A, const unsigned short* __restrict__ Bw,
    int M, int N, int K, unsigned short* o1) {
  gemm256_body<1>(A, Bw, M, N, K, o1, nullptr, nullptr);
}

// ======== 128x128 4-deep pipelined GEMM (round-8 structure, control) ========
__device__ __forceinline__ void gemm128_body(
    const unsigned short* __restrict__ A, const unsigned short* __restrict__ Bw,
    int M, int N, int K,
    const float* __restrict__ resid, float* __restrict__ outF) {
  constexpr int BUFU = 256 * 32;
  __shared__ __attribute__((aligned(16))) unsigned short lds[4 * BUFU];
  const int t = threadIdx.x, lane = t & 63, w = t >> 6;
  const int wm = w >> 2, wn = w & 3;
  const int lg = lane >> 4, ln = lane & 15;

  const int gx = gridDim.x;
  int bid = blockIdx.y * gx + blockIdx.x;
  int RX = gx >> 2, RY = gridDim.y >> 1;
  int xcd = bid & 7, c = bid >> 3;
  int bx = (xcd & 3) * RX + (c % RX);
  int by = (xcd >> 2) * RY + (c / RX);
  const int m0 = by * 128, n0 = bx * 128;

  const int nt = K >> 5;

  auto stage = [&](int tile) {
    const int buf = tile & 3;
    const int k0 = tile << 5;
    unsigned short* la = &lds[buf * BUFU];
    unsigned short* lb = la + 4096;
    int Ln = t >> 3, p = t & 7, u = p ^ (Ln & 7);
    int row = 2 * Ln + (u >> 2), cg = u & 3;
    gload_lds16(A + (size_t)(m0 + row) * K + k0 + cg * 8, &la[t * 8]);
    gload_lds16(Bw + (size_t)(n0 + row) * K + k0 + cg * 8, &lb[t * 8]);
  };

  stage(0);
  if (nt > 1) stage(1);
  if (nt > 2) stage(2);

  const unsigned base0 = lds_off(lds);
  unsigned offA[4], offB[2];
#pragma unroll
  for (int m = 0; m < 4; ++m) {
    int r = wm * 64 + m * 16 + ln;
    int Ln = r >> 1, p = ((r & 1) * 4 + lg) ^ (Ln & 7);
    offA[m] = (unsigned)((Ln * 64 + p * 8) * 2);
  }
#pragma unroll
  for (int n = 0; n < 2; ++n) {
    int r = wn * 32 + n * 16 + ln;
    int Ln = r >> 1, p = ((r & 1) * 4 + lg) ^ (Ln & 7);
    offB[n] = (unsigned)(8192 + (Ln * 64 + p * 8) * 2);
  }

  f32x4 acc[4][2] = {};

  for (int tile = 0; tile < nt; ++tile) {
    const int rem = nt - 1 - tile;
    if (rem >= 2)      { asm volatile("s_waitcnt vmcnt(4)"); }
    else if (rem == 1) { asm volatile("s_waitcnt vmcnt(2)"); }
    else               { asm volatile("s_waitcnt vmcnt(0)"); }
    __builtin_amdgcn_sched_barrier(0);
    __builtin_amdgcn_s_barrier();
    const unsigned bb = base0 + (unsigned)((tile & 3) * (BUFU * 2));
    bf16x8 af[4], bf[2];
#pragma unroll
    for (int m = 0; m < 4; ++m) af[m] = ds_read16(bb + offA[m]);
#pragma unroll
    for (int n = 0; n < 2; ++n) bf[n] = ds_read16(bb + offB[n]);
    if (tile + 3 < nt) stage(tile + 3);
    asm volatile("s_waitcnt lgkmcnt(0)");
    __builtin_amdgcn_sched_barrier(0);
    __builtin_amdgcn_s_setprio(1);
#pragma unroll
    for (int m = 0; m < 4; ++m)
#pragma unroll
      for (int n = 0; n < 2; ++n)
        acc[m][n] = __builtin_amdgcn_mfma_f32_16x16x32_bf16(af[m], bf[n], acc[m][n], 0, 0, 0);
    __builtin_amdgcn_s_setprio(0);
  }

  const int rbase = m0 + wm * 64 + lg * 4;
  const int cbase = n0 + wn * 32 + ln;
#pragma unroll
  for (int m = 0; m < 4; ++m) {
#pragma unroll
    for (int n = 0; n < 2; ++n) {
      int col = cbase + n * 16;
#pragma unroll
      for (int j = 0; j < 4; ++j) {
        int row = rbase + m * 16 + j;
        outF[(size_t)row * N + col] = acc[m][n][j] + resid[(size_t)row * N + col];
      }
    }
  }
}

__global__ __launch_bounds__(512, 4) void wo_gemm(
    const unsigned short* __restrict__ A, const unsigned short* __restrict__ Bw,
    int M, int N, int K, const float* __restrict__ resid, float* __restrict__ outF) {
  gemm128_body(A, Bw, M, N, K, resid, outF);
}
__global__ __launch_bounds__(512, 4) void ffn2_gemm(
    const unsigned short* __restrict__ A, const unsigned short* __restrict__ Bw,
    int M, int N, int K, const float* __restrict__ resid, float* __restrict__ outF) {
  gemm128_body(A, Bw, M, N, K, resid, outF);
}

// ---------------- Flash attention: QBLK=64, 4 waves, 4 blocks/CU ------------
// Q pre-scaled by (1/8)log2e. Mask-free main loop (all waves share diag tile);
// diag tile handled once after the loop. grid 1024 x 1D, chunked XCD remap.
__global__ __launch_bounds__(256, 4) void attn_kernel(
    const unsigned short* __restrict__ qg, const unsigned short* __restrict__ kg,
    const unsigned short* __restrict__ vt, unsigned short* __restrict__ og) {
  __shared__ __attribute__((aligned(16))) unsigned short Kl[2][4096];
  __shared__ __attribute__((aligned(16))) unsigned short Vl[2][4096];
  __shared__ __attribute__((aligned(16))) unsigned short Pl[4][1024];
  const int t = threadIdx.x, lane = t & 63, w = t >> 6;
  const int lg = lane >> 4, ln = lane & 15;

  // chunked XCD remap: 128 consecutive ids per XCD = 4 bh x 32 q-blocks
  int bid = blockIdx.x;
  int nl = (bid & 7) * 128 + (bid >> 3);
  int bh = nl >> 5, qxr = nl & 31;
  int b = bh >> 4, h = bh & 15;
  int q0 = (31 - qxr) * 64;  // heavy blocks first within each XCD chunk
  int qw = q0 + w * 16;

  bf16x8 aq[2];
  {
    const unsigned short* qp =
        qg + (size_t)(b * S_ + qw + ln) * D_ + h * DK_ + lg * 8;
    aq[0] = *reinterpret_cast<const bf16x8*>(qp);
    aq[1] = *reinterpret_cast<const bf16x8*>(qp + 32);
  }
  asm volatile("" : : "v"(aq[0]), "v"(aq[1]));

  float mr = -1e30f, lr = 0.f;  // stats for q = qw+ln; lr is lane-partial
  f32x4 oacc[4] = {};
  const int nt = (q0 >> 6) + 1;  // tiles 0..nt-1; nt-1 is the diag tile

  auto stage = [&](int kt) {
    const int buf = kt & 1;
    const int kv0 = kt * 64;
#pragma unroll
    for (int i = 0; i < 2; ++i) {
      int g = i * 256 + t;
      int row = g >> 3, cg = g & 7, sg = cg ^ (row & 7);
      gload_lds16(kg + (size_t)(b * S_ + kv0 + row) * D_ + h * DK_ + sg * 8, &Kl[buf][g * 8]);
      gload_lds16(vt + (size_t)(b * D_ + h * DK_ + row) * S_ + kv0 + sg * 8, &Vl[buf][g * 8]);
    }
  };
  stage(0);

  const unsigned kbase = lds_off(&Kl[0][0]);
  const unsigned vbase = lds_off(&Vl[0][0]);
  const unsigned pbase = lds_off(&Pl[w][0]);

  auto ctile = [&](int kt, bool dm) {
    const unsigned kb = kbase + (unsigned)((kt & 1) * 8192);
    const unsigned vb = vbase + (unsigned)((kt & 1) * 8192);
    // ---- QK^T (swapped: lane holds S[kv][q=ln], pre-scaled via Q) ----
    f32x4 sc[4] = {};
    bf16x8 kf[4];
#pragma unroll
    for (int n = 0; n < 4; ++n) {
      int r = n * 16 + ln;
      int cg0 = lg ^ (r & 7);
      kf[n] = ds_read16(kb + (unsigned)((r * 64 + cg0 * 8) * 2));
    }
    if (!dm) stage(kt + 1);  // next K/V DMA issued under compute
    asm volatile("s_waitcnt lgkmcnt(0)");
    __builtin_amdgcn_sched_barrier(0);
#pragma unroll
    for (int n = 0; n < 4; ++n)
      sc[n] = __builtin_amdgcn_mfma_f32_16x16x32_bf16(kf[n], aq[0], sc[n], 0, 0, 0);
#pragma unroll
    for (int n = 0; n < 4; ++n) {
      int r = n * 16 + ln;
      int cg1 = (4 + lg) ^ (r & 7);
      kf[n] = ds_read16(kb + (unsigned)((r * 64 + cg1 * 8) * 2));
    }
    asm volatile("s_waitcnt lgkmcnt(0)");
    __builtin_amdgcn_sched_barrier(0);
#pragma unroll
    for (int n = 0; n < 4; ++n)
      sc[n] = __builtin_amdgcn_mfma_f32_16x16x32_bf16(kf[n], aq[1], sc[n], 0, 0, 0);
    // ---- causal mask: diag tile only ----
    if (dm) {
      const int kv0 = kt * 64;
      const int qi = qw + ln;
#pragma unroll
      for (int n = 0; n < 4; ++n)
#pragma unroll
        for (int j = 0; j < 4; ++j)
          if ((kv0 + n * 16 + lg * 4 + j) > qi) sc[n][j] = -1e30f;
    }
    // ---- softmax: depth-4 fmax tree + 2 shfl; lr kept lane-partial ----
    float t0 = fmaxf(sc[0][0], sc[0][1]), t1 = fmaxf(sc[0][2], sc[0][3]);
    float t2 = fmaxf(sc[1][0], sc[1][1]), t3 = fmaxf(sc[1][2], sc[1][3]);
    float t4 = fmaxf(sc[2][0], sc[2][1]), t5 = fmaxf(sc[2][2], sc[2][3]);
    float t6 = fmaxf(sc[3][0], sc[3][1]), t7 = fmaxf(sc[3][2], sc[3][3]);
    t0 = fmaxf(t0, t1); t2 = fmaxf(t2, t3); t4 = fmaxf(t4, t5); t6 = fmaxf(t6, t7);
    float mx = fmaxf(fmaxf(t0, t2), fmaxf(t4, t6));
    mx = fmaxf(mx, __shfl_xor(mx, 16));
    mx = fmaxf(mx, __shfl_xor(mx, 32));
    float mn = fmaxf(mr, mx);
    float ps = 0.f;
#pragma unroll
    for (int n = 0; n < 4; ++n)
#pragma unroll
      for (int j = 0; j < 4; ++j) {
        float p = fexp2(sc[n][j] - mn);
        sc[n][j] = p;
        ps += p;
      }
    if (__all(mx <= mr)) {
      lr += ps;
    } else {
      float sf = fexp2(mr - mn);
      mr = mn;
      lr = lr * sf + ps;
#pragma unroll
      for (int j = 0; j < 4; ++j) {
        float sfj = __shfl(sf, lg * 4 + j);
#pragma unroll
        for (int f = 0; f < 4; ++f) oacc[f][j] *= sfj;
      }
    }
    // ---- P -> bf16 LDS (cvt_pk + asm b32 writes, swizzled) ----
#pragma unroll
    for (int n = 0; n < 4; ++n) {
      int kvc = n * 16 + lg * 4;
      int cg = (kvc >> 3) ^ (ln & 7);
      unsigned pa_addr = pbase + (unsigned)((ln * 64 + cg * 8 + (kvc & 7)) * 2);
      ds_write32(pa_addr, cvt_pk_bf16(sc[n][0], sc[n][1]));
      ds_write32(pa_addr + 4, cvt_pk_bf16(sc[n][2], sc[n][3]));
    }
    asm volatile("s_waitcnt lgkmcnt(0)");
    __builtin_amdgcn_sched_barrier(0);
    // ---- PV ----
#pragma unroll
    for (int c = 0; c < 2; ++c) {
      unsigned cgp = (unsigned)((c * 4 + lg) ^ (ln & 7));
      bf16x8 pa = ds_read16(pbase + (unsigned)(ln * 128) + cgp * 16);
      bf16x8 vf[4];
#pragma unroll
      for (int f = 0; f < 4; ++f) {
        int dv = f * 16 + ln;
        int cgv = (c * 4 + lg) ^ (dv & 7);
        vf[f] = ds_read16(vb + (unsigned)((dv * 64 + cgv * 8) * 2));
      }
      asm volatile("s_waitcnt lgkmcnt(0)");
      __builtin_amdgcn_sched_barrier(0);
#pragma unroll
      for (int f = 0; f < 4; ++f)
        oacc[f] = __builtin_amdgcn_mfma_f32_16x16x32_bf16(pa, vf[f], oacc[f], 0, 0, 0);
    }
  };

  for (int kt = 0; kt < nt - 1; ++kt) {
    asm volatile("s_waitcnt vmcnt(0)");
    __builtin_amdgcn_sched_barrier(0);
    __builtin_amdgcn_s_barrier();
    ctile(kt, false);
  }
  // diag tile
  asm volatile("s_waitcnt vmcnt(0)");
  __builtin_amdgcn_sched_barrier(0);
  __builtin_amdgcn_s_barrier();
  ctile(nt - 1, true);

  // final cross-lane l reduction + output
  lr += __shfl_xor(lr, 16);
  lr += __shfl_xor(lr, 32);
#pragma unroll
  for (int j = 0; j < 4; ++j) {
    float lj = __shfl(lr, lg * 4 + j);
    float inv = 1.0f / lj;
    int row = b * S_ + qw + lg * 4 + j;
#pragma unroll
    for (int f = 0; f < 4; ++f)
      og[(size_t)row * D_ + h * DK_ + f * 16 + ln] = bf16r(oacc[f][j] * inv);
  }
}

// ---------------- launch ----------------
extern "C" void kernel_launch(void* const* d_in, const int* in_sizes, int n_in,
                              void* d_out, int out_size, void* d_ws, size_t ws_size,
                              hipStream_t stream) {
  const float* x  = (const float*)d_in[0];
  const float* wq = (const float*)d_in[1];
  const float* wk = (const float*)d_in[2];
  const float* wv = (const float*)d_in[3];
  const float* wo = (const float*)d_in[4];
  const float* w1 = (const float*)d_in[5];
  const float* w2 = (const float*)d_in[6];
  const float* g1 = (const float*)d_in[7];
  const float* g2 = (const float*)d_in[8];
  float* out = (float*)d_out;

  char* ws = (char*)d_ws;
  const size_t MB = 1024 * 1024;
  unsigned short* wqkv_b = (unsigned short*)(ws + 0 * MB);   // [3072][1024]
  unsigned short* wo_b   = (unsigned short*)(ws + 6 * MB);
  unsigned short* w1_b   = (unsigned short*)(ws + 8 * MB);
  unsigned short* w2_b   = (unsigned short*)(ws + 16 * MB);
  unsigned short* h_b    = (unsigned short*)(ws + 24 * MB);
  unsigned short* q_b    = (unsigned short*)(ws + 32 * MB);
  unsigned short* k_b    = (unsigned short*)(ws + 40 * MB);
  unsigned short* vt_b   = (unsigned short*)(ws + 48 * MB);
  unsigned short* o_b    = (unsigned short*)(ws + 56 * MB);
  float*          x1     = (float*)(ws + 64 * MB);
  unsigned short* mid    = (unsigned short*)(ws + 80 * MB);

  CvtArgs ca;
  ca.src[0] = wq; ca.dst[0] = wqkv_b;
  ca.src[1] = wk; ca.dst[1] = wqkv_b + (size_t)D_ * D_;
  ca.src[2] = wv; ca.dst[2] = wqkv_b + (size_t)2 * D_ * D_;
  ca.src[3] = wo; ca.dst[3] = wo_b;
  ca.src[4] = w1; ca.dst[4] = w1_b;
  ca.src[5] = w2; ca.dst[5] = w2_b;
  int q4 = D_ * D_ / 4, f4 = F_ * D_ / 4;
  ca.start[0] = 0;
  ca.start[1] = q4;
  ca.start[2] = 2 * q4;
  ca.start[3] = 3 * q4;
  ca.start[4] = 4 * q4;
  ca.start[5] = 4 * q4 + f4;
  ca.start[6] = 4 * q4 + 2 * f4;
  cvt_all_kernel<<<(ca.start[6] + 255) / 256, 256, 0, stream>>>(ca);

  rmsnorm_kernel<<<NTOK, 256, 0, stream>>>(x, g1, h_b);

  // fused QKV: N=3072, 256x128 tiles, grid 24x16
  qkv_gemm<<<dim3(3 * D_ / 128, NTOK / 256), dim3(512), 0, stream>>>(
      h_b, wqkv_b, NTOK, 3 * D_, D_, q_b, k_b, vt_b);

  attn_kernel<<<dim3(1024), dim3(256), 0, stream>>>(q_b, k_b, vt_b, o_b);

  // WO + residual: N=1024, 128^2, grid 8x32
  wo_gemm<<<dim3(D_ / 128, NTOK / 128), dim3(512), 0, stream>>>(
      o_b, wo_b, NTOK, D_, D_, x, x1);

  rmsnorm_kernel<<<NTOK, 256, 0, stream>>>(x1, g2, h_b);

  // FFN1 + fast GELU: N=4096, 256x128 tiles, grid 32x16
  ffn1_gemm<<<dim3(F_ / 128, NTOK / 256), dim3(512), 0, stream>>>(
      h_b, w1_b, NTOK, F_, D_, mid);

  // FFN2 + residual: N=1024, 128^2, grid 8x32
  ffn2_gemm<<<dim3(D_ / 128, NTOK / 128), dim3(512), 0, stream>>>(
      mid, w2_b, NTOK, D_, F_, x1, out);
}